// Round 6
// baseline (786.772 us; speedup 1.0000x reference)
//
#include <hip/hip_runtime.h>
#include <hip/hip_bf16.h>
#include <cstdint>

// ---------------------------------------------------------------------------
// Meta-GCN LSTM encoder.  L=2, B=4, T=8, N=2048, C=2, H=64, K=3, M=32.
// R6: the 8 per-step launches per layer are fused into ONE persistent kernel
// (grid 256 = 1 block/CU, manual device-scope grid barrier).  c state lives in
// registers across steps; G chunks for step t+1 prefetched before the barrier
// spin.  Math identical to R5 (passed, absmax 0.00195).
// ---------------------------------------------------------------------------

typedef __hip_bfloat16 bf16;
typedef __attribute__((ext_vector_type(8))) short bf16x8;
typedef __attribute__((ext_vector_type(4))) short s16x4;
typedef __attribute__((ext_vector_type(4)))  float f32x4;
typedef __attribute__((ext_vector_type(16))) float f32x16;

__device__ __forceinline__ short f2bf(float f) {   // RNE f32->bf16
    unsigned u = __builtin_bit_cast(unsigned, f);
    return (short)((u + 0x7fffu + ((u >> 16) & 1u)) >> 16);
}

#define GLD_LDS(gaddr, laddr)                                                  \
    __builtin_amdgcn_global_load_lds(                                          \
        (const __attribute__((address_space(1))) void*)(gaddr),                \
        (__attribute__((address_space(3))) void*)(laddr), 16, 0, 0)

// ---------------- workspace layout (bytes) ----------------
#define OFF_GBF    0u
#define OFF_XRT0   25165824u
#define OFF_XRT1   26214400u
#define OFF_XS0T   27262976u
#define OFF_HS0T   27787264u
#define OFF_S0X    36175872u
#define OFF_S1S    36962304u
#define OFF_BAR    62128128u
#define OFF_W0SW   74711040u
#define OFF_W1SW   79429632u
#define OFF_BIAS0  85721088u
#define OFF_BIAS1  85753856u
#define WS_NEEDED  89980928u

// ---------------------------------------------------------------------------
__global__ __launch_bounds__(256) void prep_kernel(
    const float* __restrict__ G, const float* __restrict__ x_seq,
    const float* __restrict__ init_h,
    bf16* __restrict__ Gbf, bf16* __restrict__ XrT0, bf16* __restrict__ XrT1,
    bf16* __restrict__ Xs0T, unsigned* __restrict__ bar)
{
    if (blockIdx.x == 0 && threadIdx.x == 0) *bar = 0u;   // grid-barrier counter
    const int SZ_G4 = 3145728;
    const int SZ_XR = 524288, SZ_XS = 262144;
    const int TOTAL = SZ_G4 + 2*SZ_XR + SZ_XS;
    int stride = gridDim.x * 256;
    for (int idx = blockIdx.x*256 + threadIdx.x; idx < TOTAL; idx += stride) {
        int i0 = idx;
        if (i0 < SZ_G4) {
            f32x4 v = *((const f32x4*)G + i0);
            s16x4 o;
            #pragma unroll
            for (int e = 0; e < 4; e++) o[e] = f2bf(v[e]);
            *((s16x4*)Gbf + i0) = o;
            continue;
        }
        i0 -= SZ_G4;
        if (i0 < SZ_XR) {
            int n = i0 >> 11, j = i0 & 2047; int b = n >> 6, h = n & 63;
            XrT0[i0] = __float2bfloat16(init_h[((size_t)b*2048 + j)*64 + h]);
            continue;
        }
        i0 -= SZ_XR;
        if (i0 < SZ_XR) {
            int n = i0 >> 11, j = i0 & 2047; int b = n >> 6, h = n & 63;
            XrT1[i0] = __float2bfloat16(init_h[((size_t)(4+b)*2048 + j)*64 + h]);
            continue;
        }
        i0 -= SZ_XR;
        {
            int n = i0 >> 11, j = i0 & 2047;
            float v = 0.f;
            if (n < 64) {
                int t = n >> 3, rm = n & 7, b = rm >> 1, cc = rm & 1;
                v = x_seq[(((size_t)b*8 + t)*2048 + j)*2 + cc];
            }
            Xs0T[i0] = __float2bfloat16(v);
        }
    }
}

// ---------------------------------------------------------------------------
__global__ __launch_bounds__(256) void metaw_kernel(
    const float* __restrict__ x_meta,
    const float* __restrict__ lw1_0, const float* __restrict__ lb1_0,
    const float* __restrict__ lw2_0, const float* __restrict__ lb2_0,
    const float* __restrict__ bw1_0, const float* __restrict__ bb1_0,
    const float* __restrict__ bw2_0, const float* __restrict__ bb2_0,
    const float* __restrict__ lw1_1, const float* __restrict__ lb1_1,
    const float* __restrict__ lw2_1, const float* __restrict__ lb2_1,
    const float* __restrict__ bw1_1, const float* __restrict__ bb1_1,
    const float* __restrict__ bw2_1, const float* __restrict__ bb2_1,
    bf16* __restrict__ W0sw, bf16* __restrict__ W1sw,
    float* __restrict__ bias0, float* __restrict__ bias1)
{
    int tid = threadIdx.x, bid = blockIdx.x;
    const float *w1, *b1v, *w2, *b2v;
    int task, r = 0;
    if (bid < 384)      { task = 0; r = bid;       w1=lw1_1; b1v=lb1_1; w2=lw2_1; b2v=lb2_1; }
    else if (bid < 582) { task = 1; r = bid - 384; w1=lw1_0; b1v=lb1_0; w2=lw2_0; b2v=lb2_0; }
    else if (bid == 582){ task = 2;                w1=bw1_0; b1v=bb1_0; w2=bw2_0; b2v=bb2_0; }
    else                { task = 3;                w1=bw1_1; b1v=bb1_1; w2=bw2_1; b2v=bb2_1; }

    __shared__ float hid[32][64];
    for (int idx = tid; idx < 2048; idx += 256) {
        int tb = idx >> 6, h = idx & 63;
        int tt = tb >> 2, b = tb & 3;
        float a = b1v[h];
        #pragma unroll
        for (int m = 0; m < 32; m++)
            a += x_meta[((size_t)b*8 + tt)*32 + m] * w1[m*64 + h];
        hid[tb][h] = fmaxf(a, 0.f);
    }
    __syncthreads();

    int o = tid;
    int RO = (task == 0) ? 98304 : (task == 1) ? 50688 : 256;
    int ro = (task >= 2) ? o : (r*256 + o);
    float col[64];
    #pragma unroll
    for (int h = 0; h < 64; h++) col[h] = w2[(size_t)h*RO + ro];
    float base = b2v[ro];

    for (int tb = 0; tb < 32; tb++) {
        float v = base;
        #pragma unroll
        for (int h = 0; h < 64; h++) v += hid[tb][h]*col[h];
        if (task == 0) {
            int rp = r, rc = rp >> 5, rr = rp & 31;
            int oc = o >> 4, l = ((rr >> 3) << 4) + (o & 15), e = rr & 7;
            W1sw[(((size_t)tb*12 + rc)*16 + oc)*512 + l*8 + e] = __float2bfloat16(v);
        } else if (task == 1) {
            int k = r/66, d = r - k*66;
            int rp = k*96 + (d < 2 ? 64 + d : d - 2);
            int rc = rp >> 5, rr = rp & 31;
            int oc = o >> 4, l = ((rr >> 3) << 4) + (o & 15), e = rr & 7;
            W0sw[(((size_t)tb*9 + rc)*16 + oc)*512 + l*8 + e] = __float2bfloat16(v);
        } else if (task == 2) bias0[tb*256 + o] = v;
        else                  bias1[tb*256 + o] = v;
    }
}

// ---------------------------------------------------------------------------
// gemm_tile<MODE>: unchanged (proven).  MODE 1: S1s;  MODE 2: S0x.
// ---------------------------------------------------------------------------
template<int MODE>
__global__ __launch_bounds__(256) void gemm_tile(
    const short* __restrict__ A, const short* __restrict__ Bm,
    bf16* __restrict__ dstB)
{
    constexpr int NT  = (MODE == 1) ? 16 : 1;
    constexpr int NWG = 48 * NT;

    int bid  = blockIdx.x;
    int wgid = (bid & 7) * (NWG / 8) + (bid >> 3);
    int mt, nt;
    if (MODE == 1) { mt = wgid >> 4; nt = wgid & 15; }
    else           { mt = wgid; nt = 0; }

    int kk = mt >> 4;

    __shared__ short lA[128 * 64];
    __shared__ short lB[128 * 64];

    int tid = threadIdx.x, lane = tid & 63, w = tid >> 6;
    int wr = w >> 1, wc = w & 1;

    int rloc = lane >> 3;
    int gsrc = ((lane & 7) ^ rloc) * 8;
    const short* Ab = A  + (size_t)(mt * 128) * 2048 + gsrc;
    const short* Bb = Bm + (size_t)(nt * 128) * 2048 + gsrc;

    f32x4 acc[4][4];
    #pragma unroll
    for (int mf = 0; mf < 4; mf++)
        #pragma unroll
        for (int nf = 0; nf < 4; nf++)
            #pragma unroll
            for (int q = 0; q < 4; q++) acc[mf][nf][q] = 0.f;

    for (int kb = 0; kb < 2048; kb += 64) {
        #pragma unroll
        for (int q = 0; q < 4; q++) {
            int row = (w * 4 + q) * 8 + rloc;
            GLD_LDS(Ab + (size_t)row * 2048 + kb, &lA[(w * 4 + q) * 512]);
            GLD_LDS(Bb + (size_t)row * 2048 + kb, &lB[(w * 4 + q) * 512]);
        }
        __syncthreads();
        #pragma unroll
        for (int ks = 0; ks < 2; ks++) {
            bf16x8 af[4], bfr[4];
            #pragma unroll
            for (int mf = 0; mf < 4; mf++) {
                int r = wr * 64 + mf * 16 + (lane & 15);
                int cb = ((lane >> 4) * 16 + ks * 64) ^ ((r & 7) << 4);
                af[mf] = *(const bf16x8*)((const char*)lA + r * 128 + cb);
            }
            #pragma unroll
            for (int nf = 0; nf < 4; nf++) {
                int r = wc * 64 + nf * 16 + (lane & 15);
                int cb = ((lane >> 4) * 16 + ks * 64) ^ ((r & 7) << 4);
                bfr[nf] = *(const bf16x8*)((const char*)lB + r * 128 + cb);
            }
            #pragma unroll
            for (int mf = 0; mf < 4; mf++)
                #pragma unroll
                for (int nf = 0; nf < 4; nf++)
                    acc[mf][nf] = __builtin_amdgcn_mfma_f32_16x16x32_bf16(
                        af[mf], bfr[nf], acc[mf][nf], 0, 0, 0);
        }
        __syncthreads();
    }

    int l15 = lane & 15, lg4 = (lane >> 4) * 4;
    int ibase = (mt & 15) * 128 + wr * 64;
    #pragma unroll
    for (int mf = 0; mf < 4; mf++) {
        #pragma unroll
        for (int nf = 0; nf < 4; nf++) {
            int gn = nt * 128 + wc * 64 + nf * 16 + l15;
            #pragma unroll
            for (int reg = 0; reg < 4; reg++) {
                int gm = ibase + mf * 16 + lg4 + reg;
                float v = acc[mf][nf][reg];
                if (MODE == 1) {
                    int tt = gn >> 8, c = gn & 255;
                    dstB[(((size_t)tt * 3 + kk) * 2048 + gm) * 256 + c] = __float2bfloat16(v);
                } else {
                    if (gn < 64)
                        dstB[((size_t)kk * 2048 + gm) * 64 + gn] = __float2bfloat16(v);
                }
            }
        }
    }
}

// ---------------------------------------------------------------------------
// step_persist<LAYER>: ALL 8 time steps in one launch.  Grid 256 (1 block/CU,
// co-resident).  Manual device-scope grid barrier between steps; c in regs;
// G chunks for step t+1 prefetched before the barrier spin (G is static).
// ---------------------------------------------------------------------------
template<int LAYER>
__global__ __launch_bounds__(256, 1) void step_persist(
    const short* __restrict__ Gbf, const short* __restrict__ Sstat,
    const short* __restrict__ Wsw, const float* __restrict__ bias,
    const float* __restrict__ init_c, bf16* __restrict__ xrT,
    bf16* __restrict__ hs0T, float* __restrict__ out,
    unsigned* __restrict__ bar, int base)
{
    constexpr int NC = (LAYER == 0) ? 9 : 12;
    // [0,122880): 3 staging buffers (stride 40960); aliased by phase-2 partials
    // [122880,139264): sup_lds 32x512B swizzled;  [139264,143360): hT tile
    __shared__ char lds[143360];
    char* SUP = lds + 122880;
    short* hT = (short*)(lds + 139264);

    int tid = threadIdx.x, lane = tid & 63, w = tid >> 6;
    int bid = blockIdx.x;
    int q = bid >> 3;
    int it = (bid & 7) * 8 + (q >> 2), b = q & 3;
    int i0 = it * 32;
    int l31 = lane & 31, eo = lane >> 5, l15 = lane & 15, lg = lane >> 4;

    const short* xr = (const short*)xrT;
    int hcol = w * 16 + l15;

    // c state in registers for this thread's 8 (i,hcol) cells
    float creg[8];
    #pragma unroll
    for (int mi = 0; mi < 2; mi++)
        #pragma unroll
        for (int r = 0; r < 4; r++) {
            int i = i0 + mi * 16 + lg * 4 + r;
            creg[mi*4+r] = init_c[(((size_t)LAYER*4 + b)*2048 + i)*64 + hcol];
        }

    auto STAGE_G = [&](int bufi, int jb) {
        char* base_ = lds + bufi * 40960;
        #pragma unroll
        for (int qq = 0; qq < 6; qq++) {           // G: 3x32 rows x 128 j
            int g = tid + qq * 256;
            int kr = g >> 4, p = g & 15;
            int k = kr >> 5, row = kr & 31;
            const short* src = Gbf + ((size_t)(k * 2048 + i0 + row)) * 2048
                               + jb + ((p ^ (row & 15)) * 8);
            GLD_LDS(src, base_ + g * 16);
        }
    };
    auto STAGE_H = [&](int bufi, int jb) {
        char* hbase = lds + bufi * 40960 + 24576;
        #pragma unroll
        for (int qq = 0; qq < 4; qq++) {           // h^T: 64 d-rows x 128 j
            int g = tid + qq * 256;
            int d = g >> 4, p = g & 15;
            const short* src = xr + ((size_t)(b * 64 + d)) * 2048
                               + jb + ((p ^ (d & 15)) * 8);
            GLD_LDS(src, hbase + g * 16);
        }
    };

    #pragma unroll 1
    for (int t = 0; t < 8; t++) {
        f32x16 acc6[6];
        #pragma unroll
        for (int f = 0; f < 6; f++)
            #pragma unroll
            for (int r = 0; r < 16; r++) acc6[f][r] = 0.f;

        auto COMPUTE = [&](int bufi) {
            char* base_ = lds + bufi * 40960;
            char* hbase = base_ + 24576;
            #pragma unroll
            for (int ks = 0; ks < 2; ks++) {
                int jl2 = w * 64 + ks * 32 + eo * 16;
                bf16x8 a[3], bb[2];
                #pragma unroll
                for (int k = 0; k < 3; k++)
                    a[k] = *(const bf16x8*)(base_ + k * 8192 + l31 * 256
                                            + (jl2 ^ ((l31 & 15) << 4)));
                #pragma unroll
                for (int dc = 0; dc < 2; dc++) {
                    int d = dc * 32 + l31;
                    bb[dc] = *(const bf16x8*)(hbase + d * 256 + (jl2 ^ ((d & 15) << 4)));
                }
                #pragma unroll
                for (int k = 0; k < 3; k++)
                    #pragma unroll
                    for (int dc = 0; dc < 2; dc++)
                        acc6[k * 2 + dc] = __builtin_amdgcn_mfma_f32_32x32x16_bf16(
                            a[k], bb[dc], acc6[k * 2 + dc], 0, 0, 0);
            }
        };

        // ---- prologue: bufs 0,1 (t>0: G already prefetched pre-barrier) ----
        if (t == 0) {
            STAGE_G(0, 0); STAGE_H(0, 0);
            STAGE_G(1, 128); STAGE_H(1, 128);
            asm volatile("s_waitcnt vmcnt(10)" ::: "memory");
        } else {
            STAGE_H(0, 0); STAGE_H(1, 128);
            asm volatile("s_waitcnt vmcnt(4)" ::: "memory");
        }
        __builtin_amdgcn_s_barrier();

        // ---- pipelined main loop: 16 chunks of 128 j ----
        int sbuf = 2, cb = 0;
        #pragma unroll 1
        for (int m = 0; m < 16; m++) {
            if (m < 14) { STAGE_G(sbuf, (m + 2) * 128); STAGE_H(sbuf, (m + 2) * 128); }
            COMPUTE(cb);
            if (m < 14)       asm volatile("s_waitcnt vmcnt(10)" ::: "memory");
            else if (m == 14) asm volatile("s_waitcnt vmcnt(0)"  ::: "memory");
            __builtin_amdgcn_s_barrier();
            sbuf = (sbuf == 2) ? 0 : sbuf + 1;
            cb   = (cb   == 2) ? 0 : cb + 1;
        }

        // phase 2a: per-wave f32 partials (overwrites staging region)
        #pragma unroll
        for (int f = 0; f < 6; f++) {
            float* pb = (float*)(lds + (size_t)(w * 6 + f) * 4096) + lane * 16;
            #pragma unroll
            for (int qq = 0; qq < 4; qq++) {
                f32x4 v;
                #pragma unroll
                for (int r = 0; r < 4; r++) v[r] = acc6[f][qq * 4 + r];
                *(f32x4*)(pb + qq * 4) = v;
            }
        }
        __syncthreads();

        // phase 2b: reduce 4 partials -> bf16 sup_lds (swizzled)
        #pragma unroll
        for (int c2 = 0; c2 < 6; c2++) {
            int cid = c2 * 256 + tid;
            int f = cid >> 8, p0 = (cid & 255) * 4;
            f32x4 s = *(const f32x4*)(lds + (size_t)f * 4096 + p0 * 4);
            #pragma unroll
            for (int ww = 1; ww < 4; ww++) {
                f32x4 v = *(const f32x4*)(lds + (size_t)(ww * 6 + f) * 4096 + p0 * 4);
                s[0] += v[0]; s[1] += v[1]; s[2] += v[2]; s[3] += v[3];
            }
            int k = f >> 1, dc = f & 1;
            int col = (p0 >> 4) & 31, hi = p0 >> 9, r0 = p0 & 15;
            int ib = (r0 >> 2) * 8 + hi * 4;
            int dp = k * 64 + dc * 32 + col;
            #pragma unroll
            for (int u = 0; u < 4; u++) {
                int i = ib + u;
                *(short*)(SUP + i * 512 + ((dp * 2) ^ ((i & 15) << 4))) = f2bf(s[u]);
            }
        }
        __syncthreads();

        // phase 3: gemm2 (gates = sup @ W + bias)
        f32x4 ag[2][4];
        #pragma unroll
        for (int mi = 0; mi < 2; mi++)
            #pragma unroll
            for (int g = 0; g < 4; g++)
                #pragma unroll
                for (int r = 0; r < 4; r++) ag[mi][g][r] = 0.f;

        const short* WswT = Wsw + (size_t)(t * 4 + b) * NC * 16 * 512;

        #pragma unroll
        for (int rc = 0; rc < NC; rc++) {
            bf16x8 a0, a1;
            if (LAYER == 1) {
                int kk = rc >> 2, dq = rc & 3;
                if (dq < 2) {
                    const short* src = Sstat + (size_t)t * 3 * 2048 * 256;
                    int col = b * 64 + dq * 32 + lg * 8;
                    a0 = *(const bf16x8*)(src + ((size_t)kk * 2048 + i0 + l15) * 256 + col);
                    a1 = *(const bf16x8*)(src + ((size_t)kk * 2048 + i0 + 16 + l15) * 256 + col);
                } else {
                    int dpb = (kk * 64 + (dq - 2) * 32 + lg * 8) * 2;
                    a0 = *(const bf16x8*)(SUP + l15 * 512 + (dpb ^ (l15 << 4)));
                    a1 = *(const bf16x8*)(SUP + (l15 + 16) * 512 + (dpb ^ (l15 << 4)));
                }
            } else {
                int kk = rc / 3, dd = rc - kk * 3;
                if (dd < 2) {
                    int dpb = (kk * 64 + dd * 32 + lg * 8) * 2;
                    a0 = *(const bf16x8*)(SUP + l15 * 512 + (dpb ^ (l15 << 4)));
                    a1 = *(const bf16x8*)(SUP + (l15 + 16) * 512 + (dpb ^ (l15 << 4)));
                } else {
                    #pragma unroll
                    for (int e = 0; e < 8; e++) { a0[e] = 0; a1[e] = 0; }
                    if (lg == 0) {
                        unsigned v0 = *(const unsigned*)(Sstat + ((size_t)kk * 2048 + i0 + l15) * 64 + t * 8 + b * 2);
                        unsigned v1 = *(const unsigned*)(Sstat + ((size_t)kk * 2048 + i0 + 16 + l15) * 64 + t * 8 + b * 2);
                        a0[0] = (short)(v0 & 0xffff); a0[1] = (short)(v0 >> 16);
                        a1[0] = (short)(v1 & 0xffff); a1[1] = (short)(v1 >> 16);
                    }
                }
            }
            #pragma unroll
            for (int g = 0; g < 4; g++) {
                bf16x8 wf = *(const bf16x8*)(WswT + (((size_t)rc * 16 + (g * 4 + w)) * 64 + lane) * 8);
                ag[0][g] = __builtin_amdgcn_mfma_f32_16x16x32_bf16(a0, wf, ag[0][g], 0, 0, 0);
                ag[1][g] = __builtin_amdgcn_mfma_f32_16x16x32_bf16(a1, wf, ag[1][g], 0, 0, 0);
            }
        }

        float bia[4];
        #pragma unroll
        for (int g = 0; g < 4; g++) bia[g] = bias[(t * 4 + b) * 256 + g * 64 + hcol];

        // epilogue: LSTM update (c in regs); h -> LDS hT tile
        #pragma unroll
        for (int mi = 0; mi < 2; mi++) {
            #pragma unroll
            for (int r = 0; r < 4; r++) {
                int iloc = mi * 16 + lg * 4 + r;
                int i = i0 + iloc;
                float gi = ag[mi][0][r] + bia[0];
                float gf = ag[mi][1][r] + bia[1];
                float go = ag[mi][2][r] + bia[2];
                float gg = ag[mi][3][r] + bia[3];
                float c_old = creg[mi*4+r];
                float si = 1.f / (1.f + __expf(-gi));
                float sf = 1.f / (1.f + __expf(-gf));
                float so = 1.f / (1.f + __expf(-go));
                float cn = sf * c_old + si * tanhf(gg);
                float hn = so * tanhf(cn);
                creg[mi*4+r] = cn;
                hT[iloc * 64 + hcol] = f2bf(hn);
                if (t == 7) {
                    out[(((size_t)LAYER * 4 + b) * 2048 + i) * 64 + hcol]       = hn;
                    out[(((size_t)(2 + LAYER) * 4 + b) * 2048 + i) * 64 + hcol] = cn;
                }
            }
        }
        __syncthreads();

        // coalesced transposed h write-out
        {
            int row = tid >> 2, seg = tid & 3;
            bf16x8 v;
            #pragma unroll
            for (int u = 0; u < 8; u++) v[u] = hT[(seg * 8 + u) * 64 + row];
            short* dst0 = (short*)xrT + ((size_t)b * 64 + row) * 2048 + i0 + seg * 8;
            *(bf16x8*)dst0 = v;
            if (LAYER == 0) {
                short* dst1 = (short*)hs0T + ((size_t)t * 256 + b * 64 + row) * 2048 + i0 + seg * 8;
                *(bf16x8*)dst1 = v;
            }
        }

        // ---- grid barrier (device scope) + next-step G prefetch ----
        if (t < 7) {
            asm volatile("s_waitcnt vmcnt(0)" ::: "memory");   // h stores done
            __syncthreads();
            STAGE_G(0, 0); STAGE_G(1, 128);                    // static G, race-free
            if (tid == 0) {
                __hip_atomic_fetch_add(bar, 1u, __ATOMIC_RELEASE,
                                       __HIP_MEMORY_SCOPE_AGENT);
                unsigned tgt = 256u * (unsigned)(base + t + 1);
                while (__hip_atomic_load(bar, __ATOMIC_ACQUIRE,
                                         __HIP_MEMORY_SCOPE_AGENT) < tgt)
                    __builtin_amdgcn_s_sleep(2);
            }
            __syncthreads();
        }
    }
}

// ---------------------------------------------------------------------------
extern "C" void kernel_launch(void* const* d_in, const int* in_sizes, int n_in,
                              void* d_out, int out_size, void* d_ws, size_t ws_size,
                              hipStream_t stream)
{
    const float* G      = (const float*)d_in[0];
    const float* x_seq  = (const float*)d_in[1];
    const float* init_h = (const float*)d_in[2];
    const float* init_c = (const float*)d_in[3];
    const float* x_meta = (const float*)d_in[4];
    const float* lw1_0 = (const float*)d_in[5],  *lb1_0 = (const float*)d_in[6];
    const float* lw2_0 = (const float*)d_in[7],  *lb2_0 = (const float*)d_in[8];
    const float* bw1_0 = (const float*)d_in[9],  *bb1_0 = (const float*)d_in[10];
    const float* bw2_0 = (const float*)d_in[11], *bb2_0 = (const float*)d_in[12];
    const float* lw1_1 = (const float*)d_in[13], *lb1_1 = (const float*)d_in[14];
    const float* lw2_1 = (const float*)d_in[15], *lb2_1 = (const float*)d_in[16];
    const float* bw1_1 = (const float*)d_in[17], *bb1_1 = (const float*)d_in[18];
    const float* bw2_1 = (const float*)d_in[19], *bb2_1 = (const float*)d_in[20];

    if (ws_size < WS_NEEDED) return;

    char* ws = (char*)d_ws;
    bf16*  Gbf   = (bf16*) (ws + OFF_GBF);
    bf16*  XrT0  = (bf16*) (ws + OFF_XRT0);
    bf16*  XrT1  = (bf16*) (ws + OFF_XRT1);
    bf16*  Xs0T  = (bf16*) (ws + OFF_XS0T);
    bf16*  hs0T  = (bf16*) (ws + OFF_HS0T);
    bf16*  S0x   = (bf16*) (ws + OFF_S0X);
    bf16*  S1s   = (bf16*) (ws + OFF_S1S);
    unsigned* bar= (unsigned*)(ws + OFF_BAR);
    bf16*  W0sw  = (bf16*) (ws + OFF_W0SW);
    bf16*  W1sw  = (bf16*) (ws + OFF_W1SW);
    float* bias0 = (float*)(ws + OFF_BIAS0);
    float* bias1 = (float*)(ws + OFF_BIAS1);
    float* out   = (float*)d_out;

    prep_kernel<<<4096, 256, 0, stream>>>(G, x_seq, init_h,
                                          Gbf, XrT0, XrT1, Xs0T, bar);
    metaw_kernel<<<584, 256, 0, stream>>>(x_meta,
        lw1_0, lb1_0, lw2_0, lb2_0, bw1_0, bb1_0, bw2_0, bb2_0,
        lw1_1, lb1_1, lw2_1, lb2_1, bw1_1, bb1_1, bw2_1, bb2_1,
        W0sw, W1sw, bias0, bias1);

    gemm_tile<2><<<48, 256, 0, stream>>>((const short*)Gbf, (const short*)Xs0T, S0x);

    step_persist<0><<<256, 256, 0, stream>>>((const short*)Gbf, (const short*)S0x,
        (const short*)W0sw, bias0, init_c, XrT0, hs0T, out, bar, 0);

    gemm_tile<1><<<768, 256, 0, stream>>>((const short*)Gbf, (const short*)hs0T, S1s);

    step_persist<1><<<256, 256, 0, stream>>>((const short*)Gbf, (const short*)S1s,
        (const short*)W1sw, bias1, init_c, XrT1, nullptr, out, bar, 7);
}

// Round 7
// 689.477 us; speedup vs baseline: 1.1411x; 1.1411x over previous
//
#include <hip/hip_runtime.h>
#include <hip/hip_bf16.h>
#include <cstdint>

// ---------------------------------------------------------------------------
// Meta-GCN LSTM encoder.  L=2, B=4, T=8, N=2048, C=2, H=64, K=3, M=32.
// R7: R6's grid barrier spun on an ACQUIRE load -> buffer_inv per poll ->
// whole-L2 invalidation storm evicting G every step (FETCH 162MB, 45us/step).
// Fix: RELAXED spin (no inv) + RELEASE arrival (wbl2 flushes dirty h, keeps
// clean G).  Correctness without reader invalidate via per-step h ring
// buffers (each address written once, read only after).  G now L2-resident
// across all 8 steps.
// ---------------------------------------------------------------------------

typedef __hip_bfloat16 bf16;
typedef __attribute__((ext_vector_type(8))) short bf16x8;
typedef __attribute__((ext_vector_type(4))) short s16x4;
typedef __attribute__((ext_vector_type(4)))  float f32x4;
typedef __attribute__((ext_vector_type(16))) float f32x16;

__device__ __forceinline__ short f2bf(float f) {   // RNE f32->bf16
    unsigned u = __builtin_bit_cast(unsigned, f);
    return (short)((u + 0x7fffu + ((u >> 16) & 1u)) >> 16);
}

#define GLD_LDS(gaddr, laddr)                                                  \
    __builtin_amdgcn_global_load_lds(                                          \
        (const __attribute__((address_space(1))) void*)(gaddr),                \
        (__attribute__((address_space(3))) void*)(laddr), 16, 0, 0)

// ---------------- workspace layout (bytes) ----------------
#define OFF_GBF    0u           // 25165824
#define OFF_XRT0   25165824u    // 1048576
#define OFF_XRT1   26214400u    // 1048576
#define OFF_XS0T   27262976u    // 524288
#define OFF_HS0T   27787264u    // [8][256][2048] bf16 = 8388608 (layer-0 ring)
#define OFF_S0X    36175872u    // 786432
#define OFF_S1S    36962304u    // 25165824
#define OFF_RING1  62128128u    // [7][256][2048] bf16 = 7340032 (layer-1 ring)
#define OFF_W0SW   74711040u    // 4718592
#define OFF_W1SW   79429632u    // 6291456
#define OFF_BIAS0  85721088u    // 32768
#define OFF_BIAS1  85753856u    // 32768
#define OFF_BAR    85786624u    // 4
#define WS_NEEDED  89980928u

// ---------------------------------------------------------------------------
__global__ __launch_bounds__(256) void prep_kernel(
    const float* __restrict__ G, const float* __restrict__ x_seq,
    const float* __restrict__ init_h,
    bf16* __restrict__ Gbf, bf16* __restrict__ XrT0, bf16* __restrict__ XrT1,
    bf16* __restrict__ Xs0T, unsigned* __restrict__ bar)
{
    if (blockIdx.x == 0 && threadIdx.x == 0) *bar = 0u;   // grid-barrier counter
    const int SZ_G4 = 3145728;
    const int SZ_XR = 524288, SZ_XS = 262144;
    const int TOTAL = SZ_G4 + 2*SZ_XR + SZ_XS;
    int stride = gridDim.x * 256;
    for (int idx = blockIdx.x*256 + threadIdx.x; idx < TOTAL; idx += stride) {
        int i0 = idx;
        if (i0 < SZ_G4) {
            f32x4 v = *((const f32x4*)G + i0);
            s16x4 o;
            #pragma unroll
            for (int e = 0; e < 4; e++) o[e] = f2bf(v[e]);
            *((s16x4*)Gbf + i0) = o;
            continue;
        }
        i0 -= SZ_G4;
        if (i0 < SZ_XR) {
            int n = i0 >> 11, j = i0 & 2047; int b = n >> 6, h = n & 63;
            XrT0[i0] = __float2bfloat16(init_h[((size_t)b*2048 + j)*64 + h]);
            continue;
        }
        i0 -= SZ_XR;
        if (i0 < SZ_XR) {
            int n = i0 >> 11, j = i0 & 2047; int b = n >> 6, h = n & 63;
            XrT1[i0] = __float2bfloat16(init_h[((size_t)(4+b)*2048 + j)*64 + h]);
            continue;
        }
        i0 -= SZ_XR;
        {
            int n = i0 >> 11, j = i0 & 2047;
            float v = 0.f;
            if (n < 64) {
                int t = n >> 3, rm = n & 7, b = rm >> 1, cc = rm & 1;
                v = x_seq[(((size_t)b*8 + t)*2048 + j)*2 + cc];
            }
            Xs0T[i0] = __float2bfloat16(v);
        }
    }
}

// ---------------------------------------------------------------------------
__global__ __launch_bounds__(256) void metaw_kernel(
    const float* __restrict__ x_meta,
    const float* __restrict__ lw1_0, const float* __restrict__ lb1_0,
    const float* __restrict__ lw2_0, const float* __restrict__ lb2_0,
    const float* __restrict__ bw1_0, const float* __restrict__ bb1_0,
    const float* __restrict__ bw2_0, const float* __restrict__ bb2_0,
    const float* __restrict__ lw1_1, const float* __restrict__ lb1_1,
    const float* __restrict__ lw2_1, const float* __restrict__ lb2_1,
    const float* __restrict__ bw1_1, const float* __restrict__ bb1_1,
    const float* __restrict__ bw2_1, const float* __restrict__ bb2_1,
    bf16* __restrict__ W0sw, bf16* __restrict__ W1sw,
    float* __restrict__ bias0, float* __restrict__ bias1)
{
    int tid = threadIdx.x, bid = blockIdx.x;
    const float *w1, *b1v, *w2, *b2v;
    int task, r = 0;
    if (bid < 384)      { task = 0; r = bid;       w1=lw1_1; b1v=lb1_1; w2=lw2_1; b2v=lb2_1; }
    else if (bid < 582) { task = 1; r = bid - 384; w1=lw1_0; b1v=lb1_0; w2=lw2_0; b2v=lb2_0; }
    else if (bid == 582){ task = 2;                w1=bw1_0; b1v=bb1_0; w2=bw2_0; b2v=bb2_0; }
    else                { task = 3;                w1=bw1_1; b1v=bb1_1; w2=bw2_1; b2v=bb2_1; }

    __shared__ float hid[32][64];
    for (int idx = tid; idx < 2048; idx += 256) {
        int tb = idx >> 6, h = idx & 63;
        int tt = tb >> 2, b = tb & 3;
        float a = b1v[h];
        #pragma unroll
        for (int m = 0; m < 32; m++)
            a += x_meta[((size_t)b*8 + tt)*32 + m] * w1[m*64 + h];
        hid[tb][h] = fmaxf(a, 0.f);
    }
    __syncthreads();

    int o = tid;
    int RO = (task == 0) ? 98304 : (task == 1) ? 50688 : 256;
    int ro = (task >= 2) ? o : (r*256 + o);
    float col[64];
    #pragma unroll
    for (int h = 0; h < 64; h++) col[h] = w2[(size_t)h*RO + ro];
    float base = b2v[ro];

    for (int tb = 0; tb < 32; tb++) {
        float v = base;
        #pragma unroll
        for (int h = 0; h < 64; h++) v += hid[tb][h]*col[h];
        if (task == 0) {
            int rp = r, rc = rp >> 5, rr = rp & 31;
            int oc = o >> 4, l = ((rr >> 3) << 4) + (o & 15), e = rr & 7;
            W1sw[(((size_t)tb*12 + rc)*16 + oc)*512 + l*8 + e] = __float2bfloat16(v);
        } else if (task == 1) {
            int k = r/66, d = r - k*66;
            int rp = k*96 + (d < 2 ? 64 + d : d - 2);
            int rc = rp >> 5, rr = rp & 31;
            int oc = o >> 4, l = ((rr >> 3) << 4) + (o & 15), e = rr & 7;
            W0sw[(((size_t)tb*9 + rc)*16 + oc)*512 + l*8 + e] = __float2bfloat16(v);
        } else if (task == 2) bias0[tb*256 + o] = v;
        else                  bias1[tb*256 + o] = v;
    }
}

// ---------------------------------------------------------------------------
// gemm_tile<MODE>: unchanged (proven).  MODE 1: S1s;  MODE 2: S0x.
// ---------------------------------------------------------------------------
template<int MODE>
__global__ __launch_bounds__(256) void gemm_tile(
    const short* __restrict__ A, const short* __restrict__ Bm,
    bf16* __restrict__ dstB)
{
    constexpr int NT  = (MODE == 1) ? 16 : 1;
    constexpr int NWG = 48 * NT;

    int bid  = blockIdx.x;
    int wgid = (bid & 7) * (NWG / 8) + (bid >> 3);
    int mt, nt;
    if (MODE == 1) { mt = wgid >> 4; nt = wgid & 15; }
    else           { mt = wgid; nt = 0; }

    int kk = mt >> 4;

    __shared__ short lA[128 * 64];
    __shared__ short lB[128 * 64];

    int tid = threadIdx.x, lane = tid & 63, w = tid >> 6;
    int wr = w >> 1, wc = w & 1;

    int rloc = lane >> 3;
    int gsrc = ((lane & 7) ^ rloc) * 8;
    const short* Ab = A  + (size_t)(mt * 128) * 2048 + gsrc;
    const short* Bb = Bm + (size_t)(nt * 128) * 2048 + gsrc;

    f32x4 acc[4][4];
    #pragma unroll
    for (int mf = 0; mf < 4; mf++)
        #pragma unroll
        for (int nf = 0; nf < 4; nf++)
            #pragma unroll
            for (int q = 0; q < 4; q++) acc[mf][nf][q] = 0.f;

    for (int kb = 0; kb < 2048; kb += 64) {
        #pragma unroll
        for (int q = 0; q < 4; q++) {
            int row = (w * 4 + q) * 8 + rloc;
            GLD_LDS(Ab + (size_t)row * 2048 + kb, &lA[(w * 4 + q) * 512]);
            GLD_LDS(Bb + (size_t)row * 2048 + kb, &lB[(w * 4 + q) * 512]);
        }
        __syncthreads();
        #pragma unroll
        for (int ks = 0; ks < 2; ks++) {
            bf16x8 af[4], bfr[4];
            #pragma unroll
            for (int mf = 0; mf < 4; mf++) {
                int r = wr * 64 + mf * 16 + (lane & 15);
                int cb = ((lane >> 4) * 16 + ks * 64) ^ ((r & 7) << 4);
                af[mf] = *(const bf16x8*)((const char*)lA + r * 128 + cb);
            }
            #pragma unroll
            for (int nf = 0; nf < 4; nf++) {
                int r = wc * 64 + nf * 16 + (lane & 15);
                int cb = ((lane >> 4) * 16 + ks * 64) ^ ((r & 7) << 4);
                bfr[nf] = *(const bf16x8*)((const char*)lB + r * 128 + cb);
            }
            #pragma unroll
            for (int mf = 0; mf < 4; mf++)
                #pragma unroll
                for (int nf = 0; nf < 4; nf++)
                    acc[mf][nf] = __builtin_amdgcn_mfma_f32_16x16x32_bf16(
                        af[mf], bfr[nf], acc[mf][nf], 0, 0, 0);
        }
        __syncthreads();
    }

    int l15 = lane & 15, lg4 = (lane >> 4) * 4;
    int ibase = (mt & 15) * 128 + wr * 64;
    #pragma unroll
    for (int mf = 0; mf < 4; mf++) {
        #pragma unroll
        for (int nf = 0; nf < 4; nf++) {
            int gn = nt * 128 + wc * 64 + nf * 16 + l15;
            #pragma unroll
            for (int reg = 0; reg < 4; reg++) {
                int gm = ibase + mf * 16 + lg4 + reg;
                float v = acc[mf][nf][reg];
                if (MODE == 1) {
                    int tt = gn >> 8, c = gn & 255;
                    dstB[(((size_t)tt * 3 + kk) * 2048 + gm) * 256 + c] = __float2bfloat16(v);
                } else {
                    if (gn < 64)
                        dstB[((size_t)kk * 2048 + gm) * 64 + gn] = __float2bfloat16(v);
                }
            }
        }
    }
}

// ---------------------------------------------------------------------------
// step_persist<LAYER>: ALL 8 time steps in one launch.  Grid 256, 1 block/CU.
// RELAXED-spin grid barrier (no buffer_inv -> G stays L2-resident); h flows
// through per-step ring buffers (write-once, read-after -> no stale lines).
// ---------------------------------------------------------------------------
template<int LAYER>
__global__ __launch_bounds__(256, 1) void step_persist(
    const short* __restrict__ Gbf, const short* __restrict__ Sstat,
    const short* __restrict__ Wsw, const float* __restrict__ bias,
    const float* __restrict__ init_c, const bf16* __restrict__ xr_init,
    bf16* __restrict__ ring, float* __restrict__ out,
    unsigned* __restrict__ bar, int base)
{
    constexpr int NC = (LAYER == 0) ? 9 : 12;
    // [0,122880): 3 staging buffers (stride 40960); aliased by phase-2 partials
    // [122880,139264): sup_lds 32x512B swizzled;  [139264,143360): hT tile
    __shared__ char lds[143360];
    char* SUP = lds + 122880;
    short* hT = (short*)(lds + 139264);

    int tid = threadIdx.x, lane = tid & 63, w = tid >> 6;
    int bid = blockIdx.x;
    int q = bid >> 3;
    int it = (bid & 7) * 8 + (q >> 2), b = q & 3;
    int i0 = it * 32;
    int l31 = lane & 31, eo = lane >> 5, l15 = lane & 15, lg = lane >> 4;

    int hcol = w * 16 + l15;
    const short* xr = (const short*)xr_init;   // step-t h source (updated per t)

    // c state in registers
    float creg[8];
    #pragma unroll
    for (int mi = 0; mi < 2; mi++)
        #pragma unroll
        for (int r = 0; r < 4; r++) {
            int i = i0 + mi * 16 + lg * 4 + r;
            creg[mi*4+r] = init_c[(((size_t)LAYER*4 + b)*2048 + i)*64 + hcol];
        }

    auto STAGE_G = [&](int bufi, int jb) {
        char* base_ = lds + bufi * 40960;
        #pragma unroll
        for (int qq = 0; qq < 6; qq++) {           // G: 3x32 rows x 128 j
            int g = tid + qq * 256;
            int kr = g >> 4, p = g & 15;
            int k = kr >> 5, row = kr & 31;
            const short* src = Gbf + ((size_t)(k * 2048 + i0 + row)) * 2048
                               + jb + ((p ^ (row & 15)) * 8);
            GLD_LDS(src, base_ + g * 16);
        }
    };
    auto STAGE_H = [&](int bufi, int jb) {
        char* hbase = lds + bufi * 40960 + 24576;
        #pragma unroll
        for (int qq = 0; qq < 4; qq++) {           // h^T: 64 d-rows x 128 j
            int g = tid + qq * 256;
            int d = g >> 4, p = g & 15;
            const short* src = xr + ((size_t)(b * 64 + d)) * 2048
                               + jb + ((p ^ (d & 15)) * 8);
            GLD_LDS(src, hbase + g * 16);
        }
    };

    #pragma unroll 1
    for (int t = 0; t < 8; t++) {
        xr = (t == 0) ? (const short*)xr_init
                      : (const short*)ring + (size_t)(t - 1) * 524288;

        f32x16 acc6[6];
        #pragma unroll
        for (int f = 0; f < 6; f++)
            #pragma unroll
            for (int r = 0; r < 16; r++) acc6[f][r] = 0.f;

        auto COMPUTE = [&](int bufi) {
            char* base_ = lds + bufi * 40960;
            char* hbase = base_ + 24576;
            #pragma unroll
            for (int ks = 0; ks < 2; ks++) {
                int jl2 = w * 64 + ks * 32 + eo * 16;
                bf16x8 a[3], bb[2];
                #pragma unroll
                for (int k = 0; k < 3; k++)
                    a[k] = *(const bf16x8*)(base_ + k * 8192 + l31 * 256
                                            + (jl2 ^ ((l31 & 15) << 4)));
                #pragma unroll
                for (int dc = 0; dc < 2; dc++) {
                    int d = dc * 32 + l31;
                    bb[dc] = *(const bf16x8*)(hbase + d * 256 + (jl2 ^ ((d & 15) << 4)));
                }
                #pragma unroll
                for (int k = 0; k < 3; k++)
                    #pragma unroll
                    for (int dc = 0; dc < 2; dc++)
                        acc6[k * 2 + dc] = __builtin_amdgcn_mfma_f32_32x32x16_bf16(
                            a[k], bb[dc], acc6[k * 2 + dc], 0, 0, 0);
            }
        };

        // ---- prologue (t>0: G bufs 0,1 already prefetched pre-barrier) ----
        if (t == 0) {
            STAGE_G(0, 0); STAGE_H(0, 0);
            STAGE_G(1, 128); STAGE_H(1, 128);
            asm volatile("s_waitcnt vmcnt(10)" ::: "memory");
        } else {
            STAGE_H(0, 0); STAGE_H(1, 128);
            asm volatile("s_waitcnt vmcnt(4)" ::: "memory");
        }
        __builtin_amdgcn_s_barrier();

        // ---- pipelined main loop: 16 chunks of 128 j ----
        int sbuf = 2, cb = 0;
        #pragma unroll 1
        for (int m = 0; m < 16; m++) {
            if (m < 14) { STAGE_G(sbuf, (m + 2) * 128); STAGE_H(sbuf, (m + 2) * 128); }
            COMPUTE(cb);
            if (m < 14)       asm volatile("s_waitcnt vmcnt(10)" ::: "memory");
            else if (m == 14) asm volatile("s_waitcnt vmcnt(0)"  ::: "memory");
            __builtin_amdgcn_s_barrier();
            sbuf = (sbuf == 2) ? 0 : sbuf + 1;
            cb   = (cb   == 2) ? 0 : cb + 1;
        }

        // phase 2a: per-wave f32 partials (overwrites staging region)
        #pragma unroll
        for (int f = 0; f < 6; f++) {
            float* pb = (float*)(lds + (size_t)(w * 6 + f) * 4096) + lane * 16;
            #pragma unroll
            for (int qq = 0; qq < 4; qq++) {
                f32x4 v;
                #pragma unroll
                for (int r = 0; r < 4; r++) v[r] = acc6[f][qq * 4 + r];
                *(f32x4*)(pb + qq * 4) = v;
            }
        }
        __syncthreads();

        // phase 2b: reduce 4 partials -> bf16 sup_lds (swizzled)
        #pragma unroll
        for (int c2 = 0; c2 < 6; c2++) {
            int cid = c2 * 256 + tid;
            int f = cid >> 8, p0 = (cid & 255) * 4;
            f32x4 s = *(const f32x4*)(lds + (size_t)f * 4096 + p0 * 4);
            #pragma unroll
            for (int ww = 1; ww < 4; ww++) {
                f32x4 v = *(const f32x4*)(lds + (size_t)(ww * 6 + f) * 4096 + p0 * 4);
                s[0] += v[0]; s[1] += v[1]; s[2] += v[2]; s[3] += v[3];
            }
            int k = f >> 1, dc = f & 1;
            int col = (p0 >> 4) & 31, hi = p0 >> 9, r0 = p0 & 15;
            int ib = (r0 >> 2) * 8 + hi * 4;
            int dp = k * 64 + dc * 32 + col;
            #pragma unroll
            for (int u = 0; u < 4; u++) {
                int i = ib + u;
                *(short*)(SUP + i * 512 + ((dp * 2) ^ ((i & 15) << 4))) = f2bf(s[u]);
            }
        }
        __syncthreads();

        // phase 3: gemm2 (gates = sup @ W + bias)
        f32x4 ag[2][4];
        #pragma unroll
        for (int mi = 0; mi < 2; mi++)
            #pragma unroll
            for (int g = 0; g < 4; g++)
                #pragma unroll
                for (int r = 0; r < 4; r++) ag[mi][g][r] = 0.f;

        const short* WswT = Wsw + (size_t)(t * 4 + b) * NC * 16 * 512;

        #pragma unroll
        for (int rc = 0; rc < NC; rc++) {
            bf16x8 a0, a1;
            if (LAYER == 1) {
                int kk = rc >> 2, dq = rc & 3;
                if (dq < 2) {
                    const short* src = Sstat + (size_t)t * 3 * 2048 * 256;
                    int col = b * 64 + dq * 32 + lg * 8;
                    a0 = *(const bf16x8*)(src + ((size_t)kk * 2048 + i0 + l15) * 256 + col);
                    a1 = *(const bf16x8*)(src + ((size_t)kk * 2048 + i0 + 16 + l15) * 256 + col);
                } else {
                    int dpb = (kk * 64 + (dq - 2) * 32 + lg * 8) * 2;
                    a0 = *(const bf16x8*)(SUP + l15 * 512 + (dpb ^ (l15 << 4)));
                    a1 = *(const bf16x8*)(SUP + (l15 + 16) * 512 + (dpb ^ (l15 << 4)));
                }
            } else {
                int kk = rc / 3, dd = rc - kk * 3;
                if (dd < 2) {
                    int dpb = (kk * 64 + dd * 32 + lg * 8) * 2;
                    a0 = *(const bf16x8*)(SUP + l15 * 512 + (dpb ^ (l15 << 4)));
                    a1 = *(const bf16x8*)(SUP + (l15 + 16) * 512 + (dpb ^ (l15 << 4)));
                } else {
                    #pragma unroll
                    for (int e = 0; e < 8; e++) { a0[e] = 0; a1[e] = 0; }
                    if (lg == 0) {
                        unsigned v0 = *(const unsigned*)(Sstat + ((size_t)kk * 2048 + i0 + l15) * 64 + t * 8 + b * 2);
                        unsigned v1 = *(const unsigned*)(Sstat + ((size_t)kk * 2048 + i0 + 16 + l15) * 64 + t * 8 + b * 2);
                        a0[0] = (short)(v0 & 0xffff); a0[1] = (short)(v0 >> 16);
                        a1[0] = (short)(v1 & 0xffff); a1[1] = (short)(v1 >> 16);
                    }
                }
            }
            #pragma unroll
            for (int g = 0; g < 4; g++) {
                bf16x8 wf = *(const bf16x8*)(WswT + (((size_t)rc * 16 + (g * 4 + w)) * 64 + lane) * 8);
                ag[0][g] = __builtin_amdgcn_mfma_f32_16x16x32_bf16(a0, wf, ag[0][g], 0, 0, 0);
                ag[1][g] = __builtin_amdgcn_mfma_f32_16x16x32_bf16(a1, wf, ag[1][g], 0, 0, 0);
            }
        }

        float bia[4];
        #pragma unroll
        for (int g = 0; g < 4; g++) bia[g] = bias[(t * 4 + b) * 256 + g * 64 + hcol];

        // epilogue: LSTM update (c in regs); h -> LDS hT tile
        #pragma unroll
        for (int mi = 0; mi < 2; mi++) {
            #pragma unroll
            for (int r = 0; r < 4; r++) {
                int iloc = mi * 16 + lg * 4 + r;
                int i = i0 + iloc;
                float gi = ag[mi][0][r] + bia[0];
                float gf = ag[mi][1][r] + bia[1];
                float go = ag[mi][2][r] + bia[2];
                float gg = ag[mi][3][r] + bia[3];
                float c_old = creg[mi*4+r];
                float si = 1.f / (1.f + __expf(-gi));
                float sf = 1.f / (1.f + __expf(-gf));
                float so = 1.f / (1.f + __expf(-go));
                float cn = sf * c_old + si * tanhf(gg);
                float hn = so * tanhf(cn);
                creg[mi*4+r] = cn;
                hT[iloc * 64 + hcol] = f2bf(hn);
                if (t == 7) {
                    out[(((size_t)LAYER * 4 + b) * 2048 + i) * 64 + hcol]       = hn;
                    out[(((size_t)(2 + LAYER) * 4 + b) * 2048 + i) * 64 + hcol] = cn;
                }
            }
        }
        __syncthreads();

        // coalesced transposed h write-out into ring[t] (write-once address)
        if (LAYER == 0 || t < 7) {
            int row = tid >> 2, seg = tid & 3;
            bf16x8 v;
            #pragma unroll
            for (int u = 0; u < 8; u++) v[u] = hT[(seg * 8 + u) * 64 + row];
            short* dst = (short*)ring + (size_t)t * 524288
                         + ((size_t)b * 64 + row) * 2048 + i0 + seg * 8;
            *(bf16x8*)dst = v;
        }

        // ---- grid barrier: RELAXED spin (no L2 invalidate) ----
        if (t < 7) {
            asm volatile("s_waitcnt vmcnt(0)" ::: "memory");   // h stores in L2
            __syncthreads();
            STAGE_G(0, 0); STAGE_G(1, 128);   // next-step G prefetch (static)
            if (tid == 0) {
                __hip_atomic_fetch_add(bar, 1u, __ATOMIC_RELEASE,
                                       __HIP_MEMORY_SCOPE_AGENT);   // wbl2: flush h
                unsigned tgt = 256u * (unsigned)(base + t + 1);
                while (__hip_atomic_load(bar, __ATOMIC_RELAXED,
                                         __HIP_MEMORY_SCOPE_AGENT) < tgt)
                    __builtin_amdgcn_s_sleep(4);
            }
            __syncthreads();
        }
    }
}

// ---------------------------------------------------------------------------
extern "C" void kernel_launch(void* const* d_in, const int* in_sizes, int n_in,
                              void* d_out, int out_size, void* d_ws, size_t ws_size,
                              hipStream_t stream)
{
    const float* G      = (const float*)d_in[0];
    const float* x_seq  = (const float*)d_in[1];
    const float* init_h = (const float*)d_in[2];
    const float* init_c = (const float*)d_in[3];
    const float* x_meta = (const float*)d_in[4];
    const float* lw1_0 = (const float*)d_in[5],  *lb1_0 = (const float*)d_in[6];
    const float* lw2_0 = (const float*)d_in[7],  *lb2_0 = (const float*)d_in[8];
    const float* bw1_0 = (const float*)d_in[9],  *bb1_0 = (const float*)d_in[10];
    const float* bw2_0 = (const float*)d_in[11], *bb2_0 = (const float*)d_in[12];
    const float* lw1_1 = (const float*)d_in[13], *lb1_1 = (const float*)d_in[14];
    const float* lw2_1 = (const float*)d_in[15], *lb2_1 = (const float*)d_in[16];
    const float* bw1_1 = (const float*)d_in[17], *bb1_1 = (const float*)d_in[18];
    const float* bw2_1 = (const float*)d_in[19], *bb2_1 = (const float*)d_in[20];

    if (ws_size < WS_NEEDED) return;

    char* ws = (char*)d_ws;
    bf16*  Gbf   = (bf16*) (ws + OFF_GBF);
    bf16*  XrT0  = (bf16*) (ws + OFF_XRT0);
    bf16*  XrT1  = (bf16*) (ws + OFF_XRT1);
    bf16*  Xs0T  = (bf16*) (ws + OFF_XS0T);
    bf16*  hs0T  = (bf16*) (ws + OFF_HS0T);
    bf16*  S0x   = (bf16*) (ws + OFF_S0X);
    bf16*  S1s   = (bf16*) (ws + OFF_S1S);
    bf16*  ring1 = (bf16*) (ws + OFF_RING1);
    bf16*  W0sw  = (bf16*) (ws + OFF_W0SW);
    bf16*  W1sw  = (bf16*) (ws + OFF_W1SW);
    float* bias0 = (float*)(ws + OFF_BIAS0);
    float* bias1 = (float*)(ws + OFF_BIAS1);
    unsigned* bar= (unsigned*)(ws + OFF_BAR);
    float* out   = (float*)d_out;

    prep_kernel<<<4096, 256, 0, stream>>>(G, x_seq, init_h,
                                          Gbf, XrT0, XrT1, Xs0T, bar);
    metaw_kernel<<<584, 256, 0, stream>>>(x_meta,
        lw1_0, lb1_0, lw2_0, lb2_0, bw1_0, bb1_0, bw2_0, bb2_0,
        lw1_1, lb1_1, lw2_1, lb2_1, bw1_1, bb1_1, bw2_1, bb2_1,
        W0sw, W1sw, bias0, bias1);

    gemm_tile<2><<<48, 256, 0, stream>>>((const short*)Gbf, (const short*)Xs0T, S0x);

    step_persist<0><<<256, 256, 0, stream>>>((const short*)Gbf, (const short*)S0x,
        (const short*)W0sw, bias0, init_c, XrT0, hs0T, out, bar, 0);

    gemm_tile<1><<<768, 256, 0, stream>>>((const short*)Gbf, (const short*)hs0T, S1s);

    step_persist<1><<<256, 256, 0, stream>>>((const short*)Gbf, (const short*)S1s,
        (const short*)W1sw, bias1, init_c, XrT1, ring1, out, bar, 7);
}

// Round 8
// 515.200 us; speedup vs baseline: 1.5271x; 1.3383x over previous
//
#include <hip/hip_runtime.h>
#include <hip/hip_bf16.h>
#include <cstdint>

// ---------------------------------------------------------------------------
// Meta-GCN LSTM encoder.  L=2, B=4, T=8, N=2048, C=2, H=64, K=3, M=32.
// R8: revert to R5 relaunch structure (persistence regressed: L2 capacity, not
// invalidation).  step_fused now 512 threads / 8 waves -> 2 waves/SIMD (was 1,
// fully latency-exposed).  8-way K-split + pairwise reduce; same math.
// ---------------------------------------------------------------------------

typedef __hip_bfloat16 bf16;
typedef __attribute__((ext_vector_type(8))) short bf16x8;
typedef __attribute__((ext_vector_type(4))) short s16x4;
typedef __attribute__((ext_vector_type(4)))  float f32x4;
typedef __attribute__((ext_vector_type(16))) float f32x16;

__device__ __forceinline__ short f2bf(float f) {   // RNE f32->bf16
    unsigned u = __builtin_bit_cast(unsigned, f);
    return (short)((u + 0x7fffu + ((u >> 16) & 1u)) >> 16);
}

#define GLD_LDS(gaddr, laddr)                                                  \
    __builtin_amdgcn_global_load_lds(                                          \
        (const __attribute__((address_space(1))) void*)(gaddr),                \
        (__attribute__((address_space(3))) void*)(laddr), 16, 0, 0)

// ---------------- workspace layout (bytes) ----------------
#define OFF_GBF    0u
#define OFF_XRT0   25165824u
#define OFF_XRT1   26214400u
#define OFF_XS0T   27262976u
#define OFF_HS0T   27787264u
#define OFF_S0X    36175872u
#define OFF_S1S    36962304u
#define OFF_W0SW   74711040u
#define OFF_W1SW   79429632u
#define OFF_BIAS0  85721088u
#define OFF_BIAS1  85753856u
#define OFF_C0     85786624u
#define OFF_C1     87883776u
#define WS_NEEDED  89980928u

// ---------------------------------------------------------------------------
__global__ __launch_bounds__(256) void prep_kernel(
    const float* __restrict__ G, const float* __restrict__ x_seq,
    const float* __restrict__ init_h, const float* __restrict__ init_c,
    bf16* __restrict__ Gbf, bf16* __restrict__ XrT0, bf16* __restrict__ XrT1,
    bf16* __restrict__ Xs0T, float* __restrict__ c0, float* __restrict__ c1)
{
    const int SZ_G4 = 3145728;
    const int SZ_XR = 524288, SZ_XS = 262144, SZ_C = 524288;
    const int TOTAL = SZ_G4 + 2*SZ_XR + SZ_XS + 2*SZ_C;
    int stride = gridDim.x * 256;
    for (int idx = blockIdx.x*256 + threadIdx.x; idx < TOTAL; idx += stride) {
        int i0 = idx;
        if (i0 < SZ_G4) {
            f32x4 v = *((const f32x4*)G + i0);
            s16x4 o;
            #pragma unroll
            for (int e = 0; e < 4; e++) o[e] = f2bf(v[e]);
            *((s16x4*)Gbf + i0) = o;
            continue;
        }
        i0 -= SZ_G4;
        if (i0 < SZ_XR) {
            int n = i0 >> 11, j = i0 & 2047; int b = n >> 6, h = n & 63;
            XrT0[i0] = __float2bfloat16(init_h[((size_t)b*2048 + j)*64 + h]);
            continue;
        }
        i0 -= SZ_XR;
        if (i0 < SZ_XR) {
            int n = i0 >> 11, j = i0 & 2047; int b = n >> 6, h = n & 63;
            XrT1[i0] = __float2bfloat16(init_h[((size_t)(4+b)*2048 + j)*64 + h]);
            continue;
        }
        i0 -= SZ_XR;
        if (i0 < SZ_XS) {
            int n = i0 >> 11, j = i0 & 2047;
            float v = 0.f;
            if (n < 64) {
                int t = n >> 3, rm = n & 7, b = rm >> 1, cc = rm & 1;
                v = x_seq[(((size_t)b*8 + t)*2048 + j)*2 + cc];
            }
            Xs0T[i0] = __float2bfloat16(v);
            continue;
        }
        i0 -= SZ_XS;
        if (i0 < SZ_C) { c0[i0] = init_c[i0]; continue; }
        i0 -= SZ_C;
        c1[i0] = init_c[SZ_C + i0];
    }
}

// ---------------------------------------------------------------------------
__global__ __launch_bounds__(256) void metaw_kernel(
    const float* __restrict__ x_meta,
    const float* __restrict__ lw1_0, const float* __restrict__ lb1_0,
    const float* __restrict__ lw2_0, const float* __restrict__ lb2_0,
    const float* __restrict__ bw1_0, const float* __restrict__ bb1_0,
    const float* __restrict__ bw2_0, const float* __restrict__ bb2_0,
    const float* __restrict__ lw1_1, const float* __restrict__ lb1_1,
    const float* __restrict__ lw2_1, const float* __restrict__ lb2_1,
    const float* __restrict__ bw1_1, const float* __restrict__ bb1_1,
    const float* __restrict__ bw2_1, const float* __restrict__ bb2_1,
    bf16* __restrict__ W0sw, bf16* __restrict__ W1sw,
    float* __restrict__ bias0, float* __restrict__ bias1)
{
    int tid = threadIdx.x, bid = blockIdx.x;
    const float *w1, *b1v, *w2, *b2v;
    int task, r = 0;
    if (bid < 384)      { task = 0; r = bid;       w1=lw1_1; b1v=lb1_1; w2=lw2_1; b2v=lb2_1; }
    else if (bid < 582) { task = 1; r = bid - 384; w1=lw1_0; b1v=lb1_0; w2=lw2_0; b2v=lb2_0; }
    else if (bid == 582){ task = 2;                w1=bw1_0; b1v=bb1_0; w2=bw2_0; b2v=bb2_0; }
    else                { task = 3;                w1=bw1_1; b1v=bb1_1; w2=bw2_1; b2v=bb2_1; }

    __shared__ float hid[32][64];
    for (int idx = tid; idx < 2048; idx += 256) {
        int tb = idx >> 6, h = idx & 63;
        int tt = tb >> 2, b = tb & 3;
        float a = b1v[h];
        #pragma unroll
        for (int m = 0; m < 32; m++)
            a += x_meta[((size_t)b*8 + tt)*32 + m] * w1[m*64 + h];
        hid[tb][h] = fmaxf(a, 0.f);
    }
    __syncthreads();

    int o = tid;
    int RO = (task == 0) ? 98304 : (task == 1) ? 50688 : 256;
    int ro = (task >= 2) ? o : (r*256 + o);
    float col[64];
    #pragma unroll
    for (int h = 0; h < 64; h++) col[h] = w2[(size_t)h*RO + ro];
    float base = b2v[ro];

    for (int tb = 0; tb < 32; tb++) {
        float v = base;
        #pragma unroll
        for (int h = 0; h < 64; h++) v += hid[tb][h]*col[h];
        if (task == 0) {
            int rp = r, rc = rp >> 5, rr = rp & 31;
            int oc = o >> 4, l = ((rr >> 3) << 4) + (o & 15), e = rr & 7;
            W1sw[(((size_t)tb*12 + rc)*16 + oc)*512 + l*8 + e] = __float2bfloat16(v);
        } else if (task == 1) {
            int k = r/66, d = r - k*66;
            int rp = k*96 + (d < 2 ? 64 + d : d - 2);
            int rc = rp >> 5, rr = rp & 31;
            int oc = o >> 4, l = ((rr >> 3) << 4) + (o & 15), e = rr & 7;
            W0sw[(((size_t)tb*9 + rc)*16 + oc)*512 + l*8 + e] = __float2bfloat16(v);
        } else if (task == 2) bias0[tb*256 + o] = v;
        else                  bias1[tb*256 + o] = v;
    }
}

// ---------------------------------------------------------------------------
// gemm_tile<MODE>: unchanged (proven).  MODE 1: S1s;  MODE 2: S0x.
// ---------------------------------------------------------------------------
template<int MODE>
__global__ __launch_bounds__(256) void gemm_tile(
    const short* __restrict__ A, const short* __restrict__ Bm,
    bf16* __restrict__ dstB)
{
    constexpr int NT  = (MODE == 1) ? 16 : 1;
    constexpr int NWG = 48 * NT;

    int bid  = blockIdx.x;
    int wgid = (bid & 7) * (NWG / 8) + (bid >> 3);
    int mt, nt;
    if (MODE == 1) { mt = wgid >> 4; nt = wgid & 15; }
    else           { mt = wgid; nt = 0; }

    int kk = mt >> 4;

    __shared__ short lA[128 * 64];
    __shared__ short lB[128 * 64];

    int tid = threadIdx.x, lane = tid & 63, w = tid >> 6;
    int wr = w >> 1, wc = w & 1;

    int rloc = lane >> 3;
    int gsrc = ((lane & 7) ^ rloc) * 8;
    const short* Ab = A  + (size_t)(mt * 128) * 2048 + gsrc;
    const short* Bb = Bm + (size_t)(nt * 128) * 2048 + gsrc;

    f32x4 acc[4][4];
    #pragma unroll
    for (int mf = 0; mf < 4; mf++)
        #pragma unroll
        for (int nf = 0; nf < 4; nf++)
            #pragma unroll
            for (int q = 0; q < 4; q++) acc[mf][nf][q] = 0.f;

    for (int kb = 0; kb < 2048; kb += 64) {
        #pragma unroll
        for (int q = 0; q < 4; q++) {
            int row = (w * 4 + q) * 8 + rloc;
            GLD_LDS(Ab + (size_t)row * 2048 + kb, &lA[(w * 4 + q) * 512]);
            GLD_LDS(Bb + (size_t)row * 2048 + kb, &lB[(w * 4 + q) * 512]);
        }
        __syncthreads();
        #pragma unroll
        for (int ks = 0; ks < 2; ks++) {
            bf16x8 af[4], bfr[4];
            #pragma unroll
            for (int mf = 0; mf < 4; mf++) {
                int r = wr * 64 + mf * 16 + (lane & 15);
                int cb = ((lane >> 4) * 16 + ks * 64) ^ ((r & 7) << 4);
                af[mf] = *(const bf16x8*)((const char*)lA + r * 128 + cb);
            }
            #pragma unroll
            for (int nf = 0; nf < 4; nf++) {
                int r = wc * 64 + nf * 16 + (lane & 15);
                int cb = ((lane >> 4) * 16 + ks * 64) ^ ((r & 7) << 4);
                bfr[nf] = *(const bf16x8*)((const char*)lB + r * 128 + cb);
            }
            #pragma unroll
            for (int mf = 0; mf < 4; mf++)
                #pragma unroll
                for (int nf = 0; nf < 4; nf++)
                    acc[mf][nf] = __builtin_amdgcn_mfma_f32_16x16x32_bf16(
                        af[mf], bfr[nf], acc[mf][nf], 0, 0, 0);
        }
        __syncthreads();
    }

    int l15 = lane & 15, lg4 = (lane >> 4) * 4;
    int ibase = (mt & 15) * 128 + wr * 64;
    #pragma unroll
    for (int mf = 0; mf < 4; mf++) {
        #pragma unroll
        for (int nf = 0; nf < 4; nf++) {
            int gn = nt * 128 + wc * 64 + nf * 16 + l15;
            #pragma unroll
            for (int reg = 0; reg < 4; reg++) {
                int gm = ibase + mf * 16 + lg4 + reg;
                float v = acc[mf][nf][reg];
                if (MODE == 1) {
                    int tt = gn >> 8, c = gn & 255;
                    dstB[(((size_t)tt * 3 + kk) * 2048 + gm) * 256 + c] = __float2bfloat16(v);
                } else {
                    if (gn < 64)
                        dstB[((size_t)kk * 2048 + gm) * 64 + gn] = __float2bfloat16(v);
                }
            }
        }
    }
}

// ---------------------------------------------------------------------------
// step_fused<LAYER>: one launch per time step.  R8: 512 threads / 8 waves
// (2 waves/SIMD).  8-way K-split: wave w owns j-slice w*16 within each 128-j
// chunk (6 MFMA/chunk).  Pairwise cross-wave reduce keeps LDS at 96KB.
// Phase 3 split: wave group kg=w>>2 handles row-half, wh=w&3 gate columns.
// ---------------------------------------------------------------------------
template<int LAYER>
__global__ __launch_bounds__(512, 2) void step_fused(
    const short* __restrict__ Gbf, const short* __restrict__ Sstat,
    const short* __restrict__ Wsw, const float* __restrict__ bias,
    float* __restrict__ cbuf, bf16* __restrict__ xrT, bf16* __restrict__ hs0T,
    float* __restrict__ out, int t)
{
    constexpr int NC = (LAYER == 0) ? 9 : 12;
    // [0,122880): 3 staging buffers (stride 40960); aliased: reduce partials
    // [122880,139264): sup_lds 32x512B swizzled;  [139264,143360): hT tile
    __shared__ char lds[143360];
    char* SUP = lds + 122880;
    short* hT = (short*)(lds + 139264);

    int tid = threadIdx.x, lane = tid & 63, w = tid >> 6;   // w 0..7
    int wh = w & 3, kg = w >> 2;
    int bid = blockIdx.x;
    int q = bid >> 3;
    int it = (bid & 7) * 8 + (q >> 2), b = q & 3;
    int i0 = it * 32;
    int l31 = lane & 31, eo = lane >> 5, l15 = lane & 15, lg = lane >> 4;

    const short* xr = (const short*)xrT;

    f32x16 acc6[6];
    #pragma unroll
    for (int f = 0; f < 6; f++)
        #pragma unroll
        for (int r = 0; r < 16; r++) acc6[f][r] = 0.f;

    auto STAGE = [&](int bufi, int jb) {
        char* base = lds + bufi * 40960;
        #pragma unroll
        for (int qq = 0; qq < 3; qq++) {           // G: 3x32 rows x 128 j
            int g = tid + qq * 512;
            int kr = g >> 4, p = g & 15;
            int k = kr >> 5, row = kr & 31;
            const short* src = Gbf + ((size_t)(k * 2048 + i0 + row)) * 2048
                               + jb + ((p ^ (row & 15)) * 8);
            GLD_LDS(src, base + g * 16);
        }
        char* hbase = base + 24576;
        #pragma unroll
        for (int qq = 0; qq < 2; qq++) {           // h^T: 64 d-rows x 128 j
            int g = tid + qq * 512;
            int d = g >> 4, p = g & 15;
            const short* src = xr + ((size_t)(b * 64 + d)) * 2048
                               + jb + ((p ^ (d & 15)) * 8);
            GLD_LDS(src, hbase + g * 16);
        }
    };

    auto COMPUTE = [&](int bufi) {
        char* base_ = lds + bufi * 40960;
        char* hbase = base_ + 24576;
        int jl2 = w * 32 + eo * 16;                // this wave's 16-j slice
        bf16x8 a[3], bb[2];
        #pragma unroll
        for (int k = 0; k < 3; k++)
            a[k] = *(const bf16x8*)(base_ + k * 8192 + l31 * 256
                                    + (jl2 ^ ((l31 & 15) << 4)));
        #pragma unroll
        for (int dc = 0; dc < 2; dc++) {
            int d = dc * 32 + l31;
            bb[dc] = *(const bf16x8*)(hbase + d * 256 + (jl2 ^ ((d & 15) << 4)));
        }
        #pragma unroll
        for (int k = 0; k < 3; k++)
            #pragma unroll
            for (int dc = 0; dc < 2; dc++)
                acc6[k * 2 + dc] = __builtin_amdgcn_mfma_f32_32x32x16_bf16(
                    a[k], bb[dc], acc6[k * 2 + dc], 0, 0, 0);
    };

    // ---- pipelined main loop: 16 chunks of 128 j (5 loads/thread/chunk) ----
    STAGE(0, 0);
    STAGE(1, 128);
    asm volatile("s_waitcnt vmcnt(5)" ::: "memory");   // buf0 landed
    __builtin_amdgcn_s_barrier();

    int sbuf = 2, cb = 0;
    #pragma unroll 1
    for (int m = 0; m < 16; m++) {
        if (m < 14) STAGE(sbuf, (m + 2) * 128);
        COMPUTE(cb);
        if (m < 14)       asm volatile("s_waitcnt vmcnt(5)" ::: "memory");
        else if (m == 14) asm volatile("s_waitcnt vmcnt(0)" ::: "memory");
        __builtin_amdgcn_s_barrier();
        sbuf = (sbuf == 2) ? 0 : sbuf + 1;
        cb   = (cb   == 2) ? 0 : cb + 1;
    }

    // phase 2a': waves 4-7 write partials
    if (w >= 4) {
        #pragma unroll
        for (int f = 0; f < 6; f++) {
            float* pb = (float*)(lds + (size_t)((w - 4) * 6 + f) * 4096) + lane * 16;
            #pragma unroll
            for (int qq = 0; qq < 4; qq++) {
                f32x4 v;
                #pragma unroll
                for (int r = 0; r < 4; r++) v[r] = acc6[f][qq * 4 + r];
                *(f32x4*)(pb + qq * 4) = v;
            }
        }
    }
    __syncthreads();
    // phase 2b': waves 0-3 add partner partials into their accs
    if (w < 4) {
        #pragma unroll
        for (int f = 0; f < 6; f++) {
            const float* pb = (const float*)(lds + (size_t)(w * 6 + f) * 4096) + lane * 16;
            #pragma unroll
            for (int r = 0; r < 16; r++) acc6[f][r] += pb[r];
        }
    }
    __syncthreads();
    // phase 2a: waves 0-3 write combined partials
    if (w < 4) {
        #pragma unroll
        for (int f = 0; f < 6; f++) {
            float* pb = (float*)(lds + (size_t)(w * 6 + f) * 4096) + lane * 16;
            #pragma unroll
            for (int qq = 0; qq < 4; qq++) {
                f32x4 v;
                #pragma unroll
                for (int r = 0; r < 4; r++) v[r] = acc6[f][qq * 4 + r];
                *(f32x4*)(pb + qq * 4) = v;
            }
        }
    }
    __syncthreads();

    // phase 2b: all 512 threads reduce 4 partials -> bf16 sup_lds (swizzled)
    #pragma unroll
    for (int c2 = 0; c2 < 3; c2++) {
        int cid = c2 * 512 + tid;
        int f = cid >> 8, p0 = (cid & 255) * 4;
        f32x4 s = *(const f32x4*)(lds + (size_t)f * 4096 + p0 * 4);
        #pragma unroll
        for (int ww = 1; ww < 4; ww++) {
            f32x4 v = *(const f32x4*)(lds + (size_t)(ww * 6 + f) * 4096 + p0 * 4);
            s[0] += v[0]; s[1] += v[1]; s[2] += v[2]; s[3] += v[3];
        }
        int k = f >> 1, dc = f & 1;
        int col = (p0 >> 4) & 31, hi = p0 >> 9, r0 = p0 & 15;
        int ib = (r0 >> 2) * 8 + hi * 4;
        int dp = k * 64 + dc * 32 + col;
        #pragma unroll
        for (int u = 0; u < 4; u++) {
            int i = ib + u;
            *(short*)(SUP + i * 512 + ((dp * 2) ^ ((i & 15) << 4))) = f2bf(s[u]);
        }
    }
    __syncthreads();

    // phase 3: gemm2 (gates = sup @ W + bias).  Wave (kg,wh): row-half kg,
    // gate-col group wh.
    f32x4 ag[4];
    #pragma unroll
    for (int g = 0; g < 4; g++)
        #pragma unroll
        for (int r = 0; r < 4; r++) ag[g][r] = 0.f;

    const short* WswT = Wsw + (size_t)(t * 4 + b) * NC * 16 * 512;
    int rowA = kg * 16 + l15;

    #pragma unroll
    for (int rc = 0; rc < NC; rc++) {
        bf16x8 aa;
        if (LAYER == 1) {
            int kk = rc >> 2, dq = rc & 3;
            if (dq < 2) {
                const short* src = Sstat + (size_t)t * 3 * 2048 * 256;
                int col = b * 64 + dq * 32 + lg * 8;
                aa = *(const bf16x8*)(src + ((size_t)kk * 2048 + i0 + rowA) * 256 + col);
            } else {
                int dpb = (kk * 64 + (dq - 2) * 32 + lg * 8) * 2;
                aa = *(const bf16x8*)(SUP + rowA * 512 + (dpb ^ (l15 << 4)));
            }
        } else {
            int kk = rc / 3, dd = rc - kk * 3;
            if (dd < 2) {
                int dpb = (kk * 64 + dd * 32 + lg * 8) * 2;
                aa = *(const bf16x8*)(SUP + rowA * 512 + (dpb ^ (l15 << 4)));
            } else {
                #pragma unroll
                for (int e = 0; e < 8; e++) aa[e] = 0;
                if (lg == 0) {
                    unsigned v0 = *(const unsigned*)(Sstat + ((size_t)kk * 2048 + i0 + rowA) * 64 + t * 8 + b * 2);
                    aa[0] = (short)(v0 & 0xffff); aa[1] = (short)(v0 >> 16);
                }
            }
        }
        #pragma unroll
        for (int g = 0; g < 4; g++) {
            bf16x8 wf = *(const bf16x8*)(WswT + (((size_t)rc * 16 + (g * 4 + wh)) * 64 + lane) * 8);
            ag[g] = __builtin_amdgcn_mfma_f32_16x16x32_bf16(aa, wf, ag[g], 0, 0, 0);
        }
    }

    int hcol = wh * 16 + l15;
    float bia[4];
    #pragma unroll
    for (int g = 0; g < 4; g++) bia[g] = bias[(t * 4 + b) * 256 + g * 64 + hcol];

    // epilogue: LSTM update; h staged into LDS tile hT[iloc(32)][hcol(64)]
    #pragma unroll
    for (int r = 0; r < 4; r++) {
        int iloc = kg * 16 + lg * 4 + r;
        int i = i0 + iloc;
        float gi = ag[0][r] + bia[0];
        float gf = ag[1][r] + bia[1];
        float go = ag[2][r] + bia[2];
        float gg = ag[3][r] + bia[3];
        size_t cidx = ((size_t)b * 2048 + i) * 64 + hcol;
        float c_old = cbuf[cidx];
        float si = 1.f / (1.f + __expf(-gi));
        float sf = 1.f / (1.f + __expf(-gf));
        float so = 1.f / (1.f + __expf(-go));
        float cn = sf * c_old + si * tanhf(gg);
        float hn = so * tanhf(cn);
        cbuf[cidx] = cn;
        hT[iloc * 64 + hcol] = f2bf(hn);
        if (t == 7) {
            out[(((size_t)LAYER * 4 + b) * 2048 + i) * 64 + hcol]       = hn;
            out[(((size_t)(2 + LAYER) * 4 + b) * 2048 + i) * 64 + hcol] = cn;
        }
    }
    __syncthreads();

    // coalesced transposed write-out: 512 thr: row = tid>>3 (64), seg = tid&7
    {
        int row = tid >> 3, seg = tid & 7;
        s16x4 v;
        #pragma unroll
        for (int u = 0; u < 4; u++) v[u] = hT[(seg * 4 + u) * 64 + row];
        short* dst0 = (short*)xrT + ((size_t)b * 64 + row) * 2048 + i0 + seg * 4;
        *(s16x4*)dst0 = v;
        if (LAYER == 0) {
            short* dst1 = (short*)hs0T + ((size_t)t * 256 + b * 64 + row) * 2048 + i0 + seg * 4;
            *(s16x4*)dst1 = v;
        }
    }
}

// ---------------------------------------------------------------------------
extern "C" void kernel_launch(void* const* d_in, const int* in_sizes, int n_in,
                              void* d_out, int out_size, void* d_ws, size_t ws_size,
                              hipStream_t stream)
{
    const float* G      = (const float*)d_in[0];
    const float* x_seq  = (const float*)d_in[1];
    const float* init_h = (const float*)d_in[2];
    const float* init_c = (const float*)d_in[3];
    const float* x_meta = (const float*)d_in[4];
    const float* lw1_0 = (const float*)d_in[5],  *lb1_0 = (const float*)d_in[6];
    const float* lw2_0 = (const float*)d_in[7],  *lb2_0 = (const float*)d_in[8];
    const float* bw1_0 = (const float*)d_in[9],  *bb1_0 = (const float*)d_in[10];
    const float* bw2_0 = (const float*)d_in[11], *bb2_0 = (const float*)d_in[12];
    const float* lw1_1 = (const float*)d_in[13], *lb1_1 = (const float*)d_in[14];
    const float* lw2_1 = (const float*)d_in[15], *lb2_1 = (const float*)d_in[16];
    const float* bw1_1 = (const float*)d_in[17], *bb1_1 = (const float*)d_in[18];
    const float* bw2_1 = (const float*)d_in[19], *bb2_1 = (const float*)d_in[20];

    if (ws_size < WS_NEEDED) return;

    char* ws = (char*)d_ws;
    bf16*  Gbf   = (bf16*) (ws + OFF_GBF);
    bf16*  XrT0  = (bf16*) (ws + OFF_XRT0);
    bf16*  XrT1  = (bf16*) (ws + OFF_XRT1);
    bf16*  Xs0T  = (bf16*) (ws + OFF_XS0T);
    bf16*  hs0T  = (bf16*) (ws + OFF_HS0T);
    bf16*  S0x   = (bf16*) (ws + OFF_S0X);
    bf16*  S1s   = (bf16*) (ws + OFF_S1S);
    bf16*  W0sw  = (bf16*) (ws + OFF_W0SW);
    bf16*  W1sw  = (bf16*) (ws + OFF_W1SW);
    float* bias0 = (float*)(ws + OFF_BIAS0);
    float* bias1 = (float*)(ws + OFF_BIAS1);
    float* c0    = (float*)(ws + OFF_C0);
    float* c1    = (float*)(ws + OFF_C1);
    float* out   = (float*)d_out;

    prep_kernel<<<4096, 256, 0, stream>>>(G, x_seq, init_h, init_c,
                                          Gbf, XrT0, XrT1, Xs0T, c0, c1);
    metaw_kernel<<<584, 256, 0, stream>>>(x_meta,
        lw1_0, lb1_0, lw2_0, lb2_0, bw1_0, bb1_0, bw2_0, bb2_0,
        lw1_1, lb1_1, lw2_1, lb2_1, bw1_1, bb1_1, bw2_1, bb2_1,
        W0sw, W1sw, bias0, bias1);

    gemm_tile<2><<<48, 256, 0, stream>>>((const short*)Gbf, (const short*)Xs0T, S0x);

    for (int t = 0; t < 8; t++)
        step_fused<0><<<256, 512, 0, stream>>>((const short*)Gbf, (const short*)S0x,
            (const short*)W0sw, bias0, c0, XrT0, hs0T, out, t);

    gemm_tile<1><<<768, 256, 0, stream>>>((const short*)Gbf, (const short*)hs0T, S1s);

    for (int t = 0; t < 8; t++)
        step_fused<1><<<256, 512, 0, stream>>>((const short*)Gbf, (const short*)S1s,
            (const short*)W1sw, bias1, c1, XrT1, nullptr, out, t);
}

// Round 9
// 485.009 us; speedup vs baseline: 1.6222x; 1.0622x over previous
//
#include <hip/hip_runtime.h>
#include <hip/hip_bf16.h>
#include <cstdint>

// ---------------------------------------------------------------------------
// Meta-GCN LSTM encoder.  L=2, B=4, T=8, N=2048, C=2, H=64, K=3, M=32.
// R9: G stored in pre-swizzled 32x32x16 A-fragment order (Gsw); h in B-frag
// order (hfr ping-pong).  Step rec-GEMM = pure register GEMM, depth-4 pipelined
// coalesced frag loads, NO barriers in the main loop.  8-way jc split + LDS
// tree reduce -> SUP -> proven phase-3/LSTM.  gemm_tile uses Gsw A-frags too
// (drops lA staging).  Frag layouts verified numerically by R1 (passed).
// ---------------------------------------------------------------------------

typedef __hip_bfloat16 bf16;
typedef __attribute__((ext_vector_type(8))) short bf16x8;
typedef __attribute__((ext_vector_type(4))) short s16x4;
typedef __attribute__((ext_vector_type(4)))  float f32x4;
typedef __attribute__((ext_vector_type(16))) float f32x16;

__device__ __forceinline__ short f2bf(float f) {   // RNE f32->bf16
    unsigned u = __builtin_bit_cast(unsigned, f);
    return (short)((u + 0x7fffu + ((u >> 16) & 1u)) >> 16);
}

#define GLD_LDS(gaddr, laddr)                                                  \
    __builtin_amdgcn_global_load_lds(                                          \
        (const __attribute__((address_space(1))) void*)(gaddr),                \
        (__attribute__((address_space(3))) void*)(laddr), 16, 0, 0)

// ---------------- workspace layout (bytes) ----------------
#define OFF_GSW    0u           // 25165824: [k][it32(64)][jc(128)][lane(64)][8] bf16
#define OFF_HFA0   25165824u    // 1048576:  [b][jc(128)][dc(2)][lane(64)][8] bf16
#define OFF_HFA1   26214400u    // 1048576
#define OFF_XS0T   27262976u    // 524288
#define OFF_HS0T   27787264u    // 8388608: [t*256+b*64+d][j] bf16
#define OFF_S0X    36175872u    // 786432
#define OFF_S1S    36962304u    // 25165824
#define OFF_HFB0   62128128u    // 1048576
#define OFF_HFB1   63176704u    // 1048576
#define OFF_W0SW   74711040u
#define OFF_W1SW   79429632u
#define OFF_BIAS0  85721088u
#define OFF_BIAS1  85753856u
#define OFF_C0     85786624u
#define OFF_C1     87883776u
#define WS_NEEDED  89980928u

// ---------------------------------------------------------------------------
// prep: Gsw fragment-order conversion, hfr init from init_h, Xs0T, c copies.
// Gsw element (k,it32,jc,lane,e) = G[k][it32*32+(lane&31)][jc*16+(lane>>5)*8+e]
// hfr element (b,jc,dc,lane,e)   = h[jc*16+(lane>>5)*8+e][dc*32+(lane&31)]
// ---------------------------------------------------------------------------
__global__ __launch_bounds__(256) void prep_kernel(
    const float* __restrict__ G, const float* __restrict__ x_seq,
    const float* __restrict__ init_h, const float* __restrict__ init_c,
    bf16* __restrict__ Gsw, bf16* __restrict__ hfA0, bf16* __restrict__ hfA1,
    bf16* __restrict__ Xs0T, float* __restrict__ c0, float* __restrict__ c1)
{
    const int T_GS = 1572864;   // 8-short frag tasks
    const int T_HF = 131072;    // 8-short frag tasks (both layers)
    const int T_XS = 262144;    // 1 bf16 each
    const int T_C  = 1048576;   // 1 f32 each (c0 then c1)
    const int TOTAL = T_GS + T_HF + T_XS + T_C;
    int stride = gridDim.x * 256;
    for (int idx = blockIdx.x*256 + threadIdx.x; idx < TOTAL; idx += stride) {
        int i0 = idx;
        if (i0 < T_GS) {
            int lane = i0 & 63, jc = (i0 >> 6) & 127, it32 = (i0 >> 13) & 63, k = i0 >> 19;
            int row = it32*32 + (lane & 31);
            int col = jc*16 + (lane >> 5)*8;
            const float* gp = G + ((size_t)(k*2048 + row))*2048 + col;
            f32x4 v0 = *(const f32x4*)gp, v1 = *(const f32x4*)(gp + 4);
            bf16x8 o;
            #pragma unroll
            for (int e = 0; e < 4; e++) { o[e] = f2bf(v0[e]); o[e+4] = f2bf(v1[e]); }
            *(bf16x8*)((short*)Gsw + (size_t)i0*8) = o;
            continue;
        }
        i0 -= T_GS;
        if (i0 < T_HF) {
            int lane = i0 & 63, dc = (i0 >> 6) & 1, jc = (i0 >> 7) & 127;
            int b = (i0 >> 14) & 3, L = i0 >> 16;
            int j0 = jc*16 + (lane >> 5)*8, d = dc*32 + (lane & 31);
            bf16x8 o;
            #pragma unroll
            for (int e = 0; e < 8; e++)
                o[e] = f2bf(init_h[((size_t)(L*4 + b)*2048 + j0 + e)*64 + d]);
            bf16* dst = (L == 0) ? hfA0 : hfA1;
            *(bf16x8*)((short*)dst + (size_t)(i0 & 65535)*8) = o;
            continue;
        }
        i0 -= T_HF;
        if (i0 < T_XS) {
            int n = i0 >> 11, j = i0 & 2047;
            float v = 0.f;
            if (n < 64) {
                int t = n >> 3, rm = n & 7, b = rm >> 1, cc = rm & 1;
                v = x_seq[(((size_t)b*8 + t)*2048 + j)*2 + cc];
            }
            Xs0T[i0] = __float2bfloat16(v);
            continue;
        }
        i0 -= T_XS;
        if (i0 < 524288) { c0[i0] = init_c[i0]; continue; }
        i0 -= 524288;
        c1[i0] = init_c[524288 + i0];
    }
}

// ---------------------------------------------------------------------------
// metaw: unchanged (proven).
// ---------------------------------------------------------------------------
__global__ __launch_bounds__(256) void metaw_kernel(
    const float* __restrict__ x_meta,
    const float* __restrict__ lw1_0, const float* __restrict__ lb1_0,
    const float* __restrict__ lw2_0, const float* __restrict__ lb2_0,
    const float* __restrict__ bw1_0, const float* __restrict__ bb1_0,
    const float* __restrict__ bw2_0, const float* __restrict__ bb2_0,
    const float* __restrict__ lw1_1, const float* __restrict__ lb1_1,
    const float* __restrict__ lw2_1, const float* __restrict__ lb2_1,
    const float* __restrict__ bw1_1, const float* __restrict__ bb1_1,
    const float* __restrict__ bw2_1, const float* __restrict__ bb2_1,
    bf16* __restrict__ W0sw, bf16* __restrict__ W1sw,
    float* __restrict__ bias0, float* __restrict__ bias1)
{
    int tid = threadIdx.x, bid = blockIdx.x;
    const float *w1, *b1v, *w2, *b2v;
    int task, r = 0;
    if (bid < 384)      { task = 0; r = bid;       w1=lw1_1; b1v=lb1_1; w2=lw2_1; b2v=lb2_1; }
    else if (bid < 582) { task = 1; r = bid - 384; w1=lw1_0; b1v=lb1_0; w2=lw2_0; b2v=lb2_0; }
    else if (bid == 582){ task = 2;                w1=bw1_0; b1v=bb1_0; w2=bw2_0; b2v=bb2_0; }
    else                { task = 3;                w1=bw1_1; b1v=bb1_1; w2=bw2_1; b2v=bb2_1; }

    __shared__ float hid[32][64];
    for (int idx = tid; idx < 2048; idx += 256) {
        int tb = idx >> 6, h = idx & 63;
        int tt = tb >> 2, b = tb & 3;
        float a = b1v[h];
        #pragma unroll
        for (int m = 0; m < 32; m++)
            a += x_meta[((size_t)b*8 + tt)*32 + m] * w1[m*64 + h];
        hid[tb][h] = fmaxf(a, 0.f);
    }
    __syncthreads();

    int o = tid;
    int RO = (task == 0) ? 98304 : (task == 1) ? 50688 : 256;
    int ro = (task >= 2) ? o : (r*256 + o);
    float col[64];
    #pragma unroll
    for (int h = 0; h < 64; h++) col[h] = w2[(size_t)h*RO + ro];
    float base = b2v[ro];

    for (int tb = 0; tb < 32; tb++) {
        float v = base;
        #pragma unroll
        for (int h = 0; h < 64; h++) v += hid[tb][h]*col[h];
        if (task == 0) {
            int rp = r, rc = rp >> 5, rr = rp & 31;
            int oc = o >> 4, l = ((rr >> 3) << 4) + (o & 15), e = rr & 7;
            W1sw[(((size_t)tb*12 + rc)*16 + oc)*512 + l*8 + e] = __float2bfloat16(v);
        } else if (task == 1) {
            int k = r/66, d = r - k*66;
            int rp = k*96 + (d < 2 ? 64 + d : d - 2);
            int rc = rp >> 5, rr = rp & 31;
            int oc = o >> 4, l = ((rr >> 3) << 4) + (o & 15), e = rr & 7;
            W0sw[(((size_t)tb*9 + rc)*16 + oc)*512 + l*8 + e] = __float2bfloat16(v);
        } else if (task == 2) bias0[tb*256 + o] = v;
        else                  bias1[tb*256 + o] = v;
    }
}

// ---------------------------------------------------------------------------
// gemm_tile<MODE>: C = G @ B^T via Gsw A-frags (register-direct) + LDS-staged
// B.  32x32x16 MFMA, 128x128 tile, 4 waves (2x2), wave tile 64x64.
// MODE 1: S1s (B = hs0T, 16 n-tiles);  MODE 2: S0x (B = Xs0T, 1 n-tile).
// D layout (32x32): col = lane&31, row = (reg&3)+8*(reg>>2)+4*(lane>>5)  [R1]
// ---------------------------------------------------------------------------
template<int MODE>
__global__ __launch_bounds__(256) void gemm_tile(
    const short* __restrict__ Gsw, const short* __restrict__ Bm,
    bf16* __restrict__ dstB)
{
    constexpr int NT  = (MODE == 1) ? 16 : 1;
    constexpr int NWG = 48 * NT;

    int bid  = blockIdx.x;
    int wgid = (bid & 7) * (NWG / 8) + (bid >> 3);
    int mt, nt;
    if (MODE == 1) { mt = wgid >> 4; nt = wgid & 15; }
    else           { mt = wgid; nt = 0; }
    int kk = mt >> 4;

    __shared__ short lB[128 * 64];

    int tid = threadIdx.x, lane = tid & 63, w = tid >> 6;
    int wr = w >> 1, wc = w & 1;
    int l31 = lane & 31, lhi = lane >> 5;

    int rloc = lane >> 3;
    int gsrc = ((lane & 7) ^ rloc) * 8;
    const short* Bb = Bm + (size_t)(nt * 128) * 2048 + gsrc;

    f32x16 acc[2][2];
    #pragma unroll
    for (int a2 = 0; a2 < 2; a2++)
        #pragma unroll
        for (int b2 = 0; b2 < 2; b2++)
            #pragma unroll
            for (int q = 0; q < 16; q++) acc[a2][b2][q] = 0.f;

    for (int kb = 0; kb < 2048; kb += 64) {
        #pragma unroll
        for (int q = 0; q < 4; q++) {
            int row = (w * 4 + q) * 8 + rloc;
            GLD_LDS(Bb + (size_t)row * 2048 + kb, &lB[(w * 4 + q) * 512]);
        }
        __syncthreads();
        #pragma unroll
        for (int ks = 0; ks < 4; ks++) {
            int jc = (kb >> 4) + ks;
            bf16x8 af[2], bf2[2];
            #pragma unroll
            for (int a2 = 0; a2 < 2; a2++) {
                int it32 = (mt & 15) * 4 + wr * 2 + a2;
                af[a2] = *(const bf16x8*)(Gsw +
                    ((((size_t)(kk * 64 + it32)) * 128 + jc) * 64 + lane) * 8);
            }
            #pragma unroll
            for (int b2 = 0; b2 < 2; b2++) {
                int r = wc * 64 + b2 * 32 + l31;
                int cb = (ks * 32 + lhi * 16) ^ ((r & 7) << 4);
                bf2[b2] = *(const bf16x8*)((const char*)lB + r * 128 + cb);
            }
            #pragma unroll
            for (int a2 = 0; a2 < 2; a2++)
                #pragma unroll
                for (int b2 = 0; b2 < 2; b2++)
                    acc[a2][b2] = __builtin_amdgcn_mfma_f32_32x32x16_bf16(
                        af[a2], bf2[b2], acc[a2][b2], 0, 0, 0);
        }
        __syncthreads();
    }

    #pragma unroll
    for (int a2 = 0; a2 < 2; a2++) {
        #pragma unroll
        for (int b2 = 0; b2 < 2; b2++) {
            int gn = nt * 128 + wc * 64 + b2 * 32 + l31;
            #pragma unroll
            for (int reg = 0; reg < 16; reg++) {
                int gm = (mt & 15) * 128 + wr * 64 + a2 * 32
                         + (reg & 3) + 8 * (reg >> 2) + 4 * lhi;
                float v = acc[a2][b2][reg];
                if (MODE == 1) {
                    int tt = gn >> 8, c = gn & 255;
                    dstB[(((size_t)tt * 3 + kk) * 2048 + gm) * 256 + c] = __float2bfloat16(v);
                } else {
                    if (gn < 64)
                        dstB[((size_t)kk * 2048 + gm) * 64 + gn] = __float2bfloat16(v);
                }
            }
        }
    }
}

// ---------------------------------------------------------------------------
// step_fused<LAYER>: one launch per step.  512 thr / 8 waves (2/SIMD).
// Main loop: pure register GEMM over fragment-order Gsw + hfr, depth-4
// pipeline, NO barriers.  Then 3-round LDS tree reduce -> SUP -> phase3+LSTM.
// ---------------------------------------------------------------------------
#define LD(P, JC)                                                              \
    do { _Pragma("unroll") for (int k = 0; k < 3; k++)                         \
            P##a[k] = *(const bf16x8*)(Gsw +                                   \
                ((((size_t)(k * 64 + it)) * 128 + (JC)) * 64 + lane) * 8);     \
         _Pragma("unroll") for (int dc = 0; dc < 2; dc++)                      \
            P##b[dc] = *(const bf16x8*)(hfr_in +                               \
                ((((size_t)(b * 128 + (JC))) * 2 + dc) * 64 + lane) * 8);      \
    } while (0)

#define CP(P)                                                                  \
    do { _Pragma("unroll") for (int k = 0; k < 3; k++)                         \
         _Pragma("unroll") for (int dc = 0; dc < 2; dc++)                      \
            acc6[k * 2 + dc] = __builtin_amdgcn_mfma_f32_32x32x16_bf16(        \
                P##a[k], P##b[dc], acc6[k * 2 + dc], 0, 0, 0);                 \
    } while (0)

template<int LAYER>
__global__ __launch_bounds__(512, 2) void step_fused(
    const short* __restrict__ Gsw, const short* __restrict__ Sstat,
    const short* __restrict__ Wsw, const float* __restrict__ bias,
    float* __restrict__ cbuf, const short* __restrict__ hfr_in,
    short* __restrict__ hfr_out, bf16* __restrict__ hs0T,
    float* __restrict__ out, int t)
{
    constexpr int NC = (LAYER == 0) ? 9 : 12;
    // [0,98304): reduce slots (4 x 24KB); [98304,114688): SUP; [114688,118784): hT
    __shared__ char lds[118784];
    char* SUP = lds + 98304;
    short* hT = (short*)(lds + 114688);
    float* RB = (float*)lds;

    int tid = threadIdx.x, lane = tid & 63, w = tid >> 6;   // 8 waves
    int wh = w & 3, kg = w >> 2;
    int bid = blockIdx.x;
    int q = bid >> 3;
    int it = (bid & 7) * 8 + (q >> 2), b = q & 3;           // XCD-pinned
    int i0 = it * 32;
    int l31 = lane & 31, lhi = lane >> 5, l15 = lane & 15, lg = lane >> 4;

    f32x16 acc6[6];
    #pragma unroll
    for (int f = 0; f < 6; f++)
        #pragma unroll
        for (int r = 0; r < 16; r++) acc6[f][r] = 0.f;

    // ---- main loop: 16 jc chunks per wave, depth-4 register pipeline ----
    {
        int jc0 = w * 16;
        bf16x8 fAa[3], fAb[2], fBa[3], fBb[2], fCa[3], fCb[2], fDa[3], fDb[2];
        LD(fA, jc0 + 0); LD(fB, jc0 + 1); LD(fC, jc0 + 2); LD(fD, jc0 + 3);
        #pragma unroll 1
        for (int j4 = 0; j4 < 3; j4++) {
            CP(fA); LD(fA, jc0 + j4 * 4 + 4);
            CP(fB); LD(fB, jc0 + j4 * 4 + 5);
            CP(fC); LD(fC, jc0 + j4 * 4 + 6);
            CP(fD); LD(fD, jc0 + j4 * 4 + 7);
        }
        CP(fA); CP(fB); CP(fC); CP(fD);
    }

    // ---- 3-round tree reduce: 8 waves -> wave 0, then SUP (bf16, swizzled) --
    if (w >= 4) {
        #pragma unroll
        for (int f = 0; f < 6; f++)
            #pragma unroll
            for (int qq = 0; qq < 4; qq++) {
                f32x4 v;
                #pragma unroll
                for (int r = 0; r < 4; r++) v[r] = acc6[f][qq * 4 + r];
                *(f32x4*)(RB + ((size_t)((w - 4) * 6 + f)) * 1024 + lane * 16 + qq * 4) = v;
            }
    }
    __syncthreads();
    if (w < 4) {
        #pragma unroll
        for (int f = 0; f < 6; f++)
            #pragma unroll
            for (int r = 0; r < 16; r++)
                acc6[f][r] += RB[((size_t)(w * 6 + f)) * 1024 + lane * 16 + r];
    }
    __syncthreads();
    if (w == 2 || w == 3) {
        #pragma unroll
        for (int f = 0; f < 6; f++)
            #pragma unroll
            for (int qq = 0; qq < 4; qq++) {
                f32x4 v;
                #pragma unroll
                for (int r = 0; r < 4; r++) v[r] = acc6[f][qq * 4 + r];
                *(f32x4*)(RB + ((size_t)((w - 2) * 6 + f)) * 1024 + lane * 16 + qq * 4) = v;
            }
    }
    __syncthreads();
    if (w < 2) {
        #pragma unroll
        for (int f = 0; f < 6; f++)
            #pragma unroll
            for (int r = 0; r < 16; r++)
                acc6[f][r] += RB[((size_t)(w * 6 + f)) * 1024 + lane * 16 + r];
    }
    __syncthreads();
    if (w == 1) {
        #pragma unroll
        for (int f = 0; f < 6; f++)
            #pragma unroll
            for (int qq = 0; qq < 4; qq++) {
                f32x4 v;
                #pragma unroll
                for (int r = 0; r < 4; r++) v[r] = acc6[f][qq * 4 + r];
                *(f32x4*)(RB + (size_t)f * 1024 + lane * 16 + qq * 4) = v;
            }
    }
    __syncthreads();
    if (w == 0) {
        #pragma unroll
        for (int f = 0; f < 6; f++) {
            int k = f >> 1, dc = f & 1;
            #pragma unroll
            for (int reg = 0; reg < 16; reg++) {
                float s = acc6[f][reg] + RB[(size_t)f * 1024 + lane * 16 + reg];
                int i = (reg & 3) + 8 * (reg >> 2) + 4 * lhi;
                int dpos = k * 64 + dc * 32 + l31;
                *(short*)(SUP + i * 512 + ((dpos * 2) ^ ((i & 15) << 4))) = f2bf(s);
            }
        }
    }
    __syncthreads();

    // ---- phase 3: gemm2 (gates = sup @ W + bias); wave (kg rows, wh gates) --
    f32x4 ag[4];
    #pragma unroll
    for (int g = 0; g < 4; g++)
        #pragma unroll
        for (int r = 0; r < 4; r++) ag[g][r] = 0.f;

    const short* WswT = Wsw + (size_t)(t * 4 + b) * NC * 16 * 512;
    int rowA = kg * 16 + l15;

    #pragma unroll
    for (int rc = 0; rc < NC; rc++) {
        bf16x8 aa;
        if (LAYER == 1) {
            int kk = rc >> 2, dq = rc & 3;
            if (dq < 2) {
                const short* src = Sstat + (size_t)t * 3 * 2048 * 256;
                int col = b * 64 + dq * 32 + lg * 8;
                aa = *(const bf16x8*)(src + ((size_t)kk * 2048 + i0 + rowA) * 256 + col);
            } else {
                int dpb = (kk * 64 + (dq - 2) * 32 + lg * 8) * 2;
                aa = *(const bf16x8*)(SUP + rowA * 512 + (dpb ^ (l15 << 4)));
            }
        } else {
            int kk = rc / 3, dd = rc - kk * 3;
            if (dd < 2) {
                int dpb = (kk * 64 + dd * 32 + lg * 8) * 2;
                aa = *(const bf16x8*)(SUP + rowA * 512 + (dpb ^ (l15 << 4)));
            } else {
                #pragma unroll
                for (int e = 0; e < 8; e++) aa[e] = 0;
                if (lg == 0) {
                    unsigned v0 = *(const unsigned*)(Sstat + ((size_t)kk * 2048 + i0 + rowA) * 64 + t * 8 + b * 2);
                    aa[0] = (short)(v0 & 0xffff); aa[1] = (short)(v0 >> 16);
                }
            }
        }
        #pragma unroll
        for (int g = 0; g < 4; g++) {
            bf16x8 wf = *(const bf16x8*)(WswT + (((size_t)rc * 16 + (g * 4 + wh)) * 64 + lane) * 8);
            ag[g] = __builtin_amdgcn_mfma_f32_16x16x32_bf16(aa, wf, ag[g], 0, 0, 0);
        }
    }

    int hcol = wh * 16 + l15;
    float bia[4];
    #pragma unroll
    for (int g = 0; g < 4; g++) bia[g] = bias[(t * 4 + b) * 256 + g * 64 + hcol];

    // ---- LSTM epilogue; h -> LDS hT ----
    #pragma unroll
    for (int r = 0; r < 4; r++) {
        int iloc = kg * 16 + lg * 4 + r;
        int i = i0 + iloc;
        float gi = ag[0][r] + bia[0];
        float gf = ag[1][r] + bia[1];
        float go = ag[2][r] + bia[2];
        float gg = ag[3][r] + bia[3];
        size_t cidx = ((size_t)b * 2048 + i) * 64 + hcol;
        float c_old = cbuf[cidx];
        float si = 1.f / (1.f + __expf(-gi));
        float sf = 1.f / (1.f + __expf(-gf));
        float so = 1.f / (1.f + __expf(-go));
        float cn = sf * c_old + si * tanhf(gg);
        float hn = so * tanhf(cn);
        cbuf[cidx] = cn;
        hT[iloc * 64 + hcol] = f2bf(hn);
        if (t == 7) {
            out[(((size_t)LAYER * 4 + b) * 2048 + i) * 64 + hcol]       = hn;
            out[(((size_t)(2 + LAYER) * 4 + b) * 2048 + i) * 64 + hcol] = cn;
        }
    }
    __syncthreads();

    // ---- write h in B-frag order for next step ----
    {
        int tile = tid >> 7, wl = (tid >> 1) & 63, half = tid & 1;
        int jh = tile >> 1, dc = tile & 1;
        s16x4 v;
        #pragma unroll
        for (int u = 0; u < 4; u++)
            v[u] = hT[(jh * 16 + (wl >> 5) * 8 + half * 4 + u) * 64 + dc * 32 + (wl & 31)];
        *(s16x4*)(hfr_out +
            ((((size_t)(b * 128 + it * 2 + jh)) * 2 + dc) * 64 + wl) * 8 + half * 4) = v;
    }
    // ---- layer 0: also write row-major hs0T for the S1s GEMM ----
    if (LAYER == 0) {
        int row = tid >> 3, seg = tid & 7;
        s16x4 v;
        #pragma unroll
        for (int u = 0; u < 4; u++) v[u] = hT[(seg * 4 + u) * 64 + row];
        short* dst = (short*)hs0T + ((size_t)t * 256 + b * 64 + row) * 2048 + i0 + seg * 4;
        *(s16x4*)dst = v;
    }
}

// ---------------------------------------------------------------------------
extern "C" void kernel_launch(void* const* d_in, const int* in_sizes, int n_in,
                              void* d_out, int out_size, void* d_ws, size_t ws_size,
                              hipStream_t stream)
{
    const float* G      = (const float*)d_in[0];
    const float* x_seq  = (const float*)d_in[1];
    const float* init_h = (const float*)d_in[2];
    const float* init_c = (const float*)d_in[3];
    const float* x_meta = (const float*)d_in[4];
    const float* lw1_0 = (const float*)d_in[5],  *lb1_0 = (const float*)d_in[6];
    const float* lw2_0 = (const float*)d_in[7],  *lb2_0 = (const float*)d_in[8];
    const float* bw1_0 = (const float*)d_in[9],  *bb1_0 = (const float*)d_in[10];
    const float* bw2_0 = (const float*)d_in[11], *bb2_0 = (const float*)d_in[12];
    const float* lw1_1 = (const float*)d_in[13], *lb1_1 = (const float*)d_in[14];
    const float* lw2_1 = (const float*)d_in[15], *lb2_1 = (const float*)d_in[16];
    const float* bw1_1 = (const float*)d_in[17], *bb1_1 = (const float*)d_in[18];
    const float* bw1_1b= bw1_1;
    const float* bw2_1 = (const float*)d_in[19], *bb2_1 = (const float*)d_in[20];
    (void)bw1_1b;

    if (ws_size < WS_NEEDED) return;

    char* ws = (char*)d_ws;
    bf16*  Gsw   = (bf16*) (ws + OFF_GSW);
    bf16*  hfA0  = (bf16*) (ws + OFF_HFA0);
    bf16*  hfA1  = (bf16*) (ws + OFF_HFA1);
    bf16*  Xs0T  = (bf16*) (ws + OFF_XS0T);
    bf16*  hs0T  = (bf16*) (ws + OFF_HS0T);
    bf16*  S0x   = (bf16*) (ws + OFF_S0X);
    bf16*  S1s   = (bf16*) (ws + OFF_S1S);
    bf16*  hfB0  = (bf16*) (ws + OFF_HFB0);
    bf16*  hfB1  = (bf16*) (ws + OFF_HFB1);
    bf16*  W0sw  = (bf16*) (ws + OFF_W0SW);
    bf16*  W1sw  = (bf16*) (ws + OFF_W1SW);
    float* bias0 = (float*)(ws + OFF_BIAS0);
    float* bias1 = (float*)(ws + OFF_BIAS1);
    float* c0    = (float*)(ws + OFF_C0);
    float* c1    = (float*)(ws + OFF_C1);
    float* out   = (float*)d_out;

    prep_kernel<<<4096, 256, 0, stream>>>(G, x_seq, init_h, init_c,
                                          Gsw, hfA0, hfA1, Xs0T, c0, c1);
    metaw_kernel<<<584, 256, 0, stream>>>(x_meta,
        lw1_0, lb1_0, lw2_0, lb2_0, bw1_0, bb1_0, bw2_0, bb2_0,
        lw1_1, lb1_1, lw2_1, lb2_1, bw1_1, bb1_1, bw2_1, bb2_1,
        W0sw, W1sw, bias0, bias1);

    gemm_tile<2><<<48, 256, 0, stream>>>((const short*)Gsw, (const short*)Xs0T, S0x);

    for (int t = 0; t < 8; t++) {
        const short* hin  = (const short*)((t & 1) ? hfB0 : hfA0);
        short*       hout = (short*)((t & 1) ? hfA0 : hfB0);
        step_fused<0><<<256, 512, 0, stream>>>((const short*)Gsw, (const short*)S0x,
            (const short*)W0sw, bias0, c0, hin, hout, hs0T, out, t);
    }

    gemm_tile<1><<<768, 256, 0, stream>>>((const short*)Gsw, (const short*)hs0T, S1s);

    for (int t = 0; t < 8; t++) {
        const short* hin  = (const short*)((t & 1) ? hfB1 : hfA1);
        short*       hout = (short*)((t & 1) ? hfA1 : hfB1);
        step_fused<1><<<256, 512, 0, stream>>>((const short*)Gsw, (const short*)S1s,
            (const short*)W1sw, bias1, c1, hin, hout, nullptr, out, t);
    }
}